// Round 3
// baseline (1978.518 us; speedup 1.0000x reference)
//
#include <hip/hip_runtime.h>

__device__ inline unsigned short f2bf(float f) {
    unsigned u = __float_as_uint(f);
    unsigned r = (u + 0x7fffu + ((u >> 16) & 1u)) >> 16;   // round-nearest-even
    return (unsigned short)r;
}

// ---------------- CSR build (rank captured in count pass; fill is atomic-free) ----------------
__global__ void count_rank_kernel(const int* __restrict__ from_idx, const int* __restrict__ to_idx,
                                  int* __restrict__ cnt_to, int* __restrict__ cnt_from,
                                  int* __restrict__ rank_to, int* __restrict__ rank_from, int E) {
    int e = blockIdx.x * blockDim.x + threadIdx.x;
    if (e >= E) return;
    int f = from_idx[e], t = to_idx[e];
    rank_to[e] = atomicAdd(&cnt_to[t], 1);
    rank_from[e] = atomicAdd(&cnt_from[f], 1);
}

__global__ void scan2_kernel(const int* __restrict__ cnt_to, int* __restrict__ off_to,
                             const int* __restrict__ cnt_from, int* __restrict__ off_from, int n) {
    const int* cnt = blockIdx.x ? cnt_from : cnt_to;
    int* off = blockIdx.x ? off_from : off_to;
    __shared__ int part[1024];
    int tid = threadIdx.x;
    int chunk = (n + 1023) >> 10;
    int beg = tid * chunk, end = min(beg + chunk, n);
    int s = 0;
    for (int i = beg; i < end; ++i) s += cnt[i];
    part[tid] = s;
    __syncthreads();
    for (int d = 1; d < 1024; d <<= 1) {
        int v = part[tid];
        int add = (tid >= d) ? part[tid - d] : 0;
        __syncthreads();
        part[tid] = v + add;
        __syncthreads();
    }
    int base = part[tid] - s;
    for (int i = beg; i < end; ++i) { off[i] = base; base += cnt[i]; }
    if (tid == 1023) off[n] = part[1023];
}

__global__ void fill_kernel(const int* __restrict__ from_idx, const int* __restrict__ to_idx,
                            const int* __restrict__ off_to, const int* __restrict__ off_from,
                            const int* __restrict__ rank_to, const int* __restrict__ rank_from,
                            int* __restrict__ list_to, int* __restrict__ list_from, int E) {
    int e = blockIdx.x * blockDim.x + threadIdx.x;
    if (e >= E) return;
    int f = from_idx[e], t = to_idx[e];
    list_to[off_to[t] + rank_to[e]] = f;
    list_from[off_from[f] + rank_from[e]] = t;
}

// ---------------- weight transposes (GRU uses x @ W.T) ----------------
__global__ void transpose_all(const float* __restrict__ Wih, const float* __restrict__ Whh,
                              float* __restrict__ WihT, float* __restrict__ WhhT) {
    int idx = blockIdx.x * 256 + threadIdx.x;
    if (idx < 3 * 96 * 96) {
        int l = idx / 9216, r = idx % 9216;
        int j = r / 96, k = r % 96;
        WihT[idx] = Wih[l * 9216 + k * 96 + j];
    } else if (idx < 3 * 96 * 96 + 3 * 32 * 96) {
        int i2 = idx - 3 * 96 * 96;
        int l = i2 / 3072, r = i2 % 3072;
        int j = r / 96, k = r % 96;
        WhhT[i2] = Whh[l * 3072 + k * 32 + j];
    }
}

// ---------------- encoder: h = IN@W + b, plus bf16 copy ----------------
__global__ void __launch_bounds__(256) enc_gemm(const float* __restrict__ IN,
                                                const float* __restrict__ W, const float* __restrict__ bias,
                                                float* __restrict__ OUT, unsigned short* __restrict__ hbf, int N) {
    __shared__ float tile[64][33];
    int n0 = blockIdx.x * 64, tid = threadIdx.x;
    for (int idx = tid; idx < 64 * 32; idx += 256) {
        int r = idx >> 5, c = idx & 31;
        int n = n0 + r;
        tile[r][c] = (n < N) ? IN[(long)n * 32 + c] : 0.f;
    }
    __syncthreads();
    int lane = tid & 63, w = tid >> 6;
    float acc[8] = {0};
    const float* Wp = W + w * 8;
#pragma unroll
    for (int j = 0; j < 32; ++j) {
        float a = tile[lane][j];
#pragma unroll
        for (int c = 0; c < 8; ++c) acc[c] = fmaf(a, Wp[j * 32 + c], acc[c]);
    }
    int n = n0 + lane;
    if (n >= N) return;
    float* outp = OUT + (long)n * 32 + w * 8;
    unsigned short* bp = hbf + (long)n * 32 + w * 8;
#pragma unroll
    for (int c = 0; c < 8; ++c) {
        float v = acc[c] + bias[w * 8 + c];
        outp[c] = v;
        bp[c] = f2bf(v);
    }
}

// ---------------- dst-side projections only: Pb = h @ W1[32:64] + b1 (y: fwd/rev) ----------------
__global__ void __launch_bounds__(256) proj_kernel(
    const float* __restrict__ h,
    const float* __restrict__ W1f, const float* __restrict__ b1f,
    const float* __restrict__ W1r, const float* __restrict__ b1r,
    float* __restrict__ PbF, float* __restrict__ PbR, int N)
{
    const float* W1 = (blockIdx.y ? W1r : W1f) + 32 * 96;   // dst-half rows
    const float* b1 = blockIdx.y ? b1r : b1f;
    float* Pb = blockIdx.y ? PbR : PbF;
    __shared__ float tile[64][33];
    int n0 = blockIdx.x * 64, tid = threadIdx.x;
    for (int idx = tid; idx < 64 * 32; idx += 256) {
        int r = idx >> 5, c = idx & 31;
        int n = n0 + r;
        tile[r][c] = (n < N) ? h[(long)n * 32 + c] : 0.f;
    }
    __syncthreads();
    int lane = tid & 63, w = tid >> 6;
    float acc[24];
#pragma unroll
    for (int c = 0; c < 24; ++c) acc[c] = 0.f;
    const float* Wp = W1 + w * 24;
#pragma unroll 4
    for (int j = 0; j < 32; ++j) {
        float a = tile[lane][j];
#pragma unroll
        for (int c = 0; c < 24; ++c) acc[c] = fmaf(a, Wp[j * 96 + c], acc[c]);
    }
    int n = n0 + lane;
    if (n >= N) return;
    float* outp = Pb + (long)n * 96 + w * 24;
#pragma unroll
    for (int c = 0; c < 24; ++c) outp[c] = acc[c] + b1[w * 24 + c];
}

// ---------------- fused edge aggregation: gather bf16 h[src] (64 B, L2-resident),
// project 32->96 on the fly (weights in VGPRs), relu, accumulate per node ----------------
__global__ void __launch_bounds__(256) agg_fused(
    const int* __restrict__ offF, const int* __restrict__ listF,
    const int* __restrict__ offR, const int* __restrict__ listR,
    const unsigned short* __restrict__ hbf,
    const float* __restrict__ WaF, const float* __restrict__ WaR,  // src-half rows [32][96]
    float* PbF, float* PbR, int N)
{
    const int* off; const int* list; const float* Wa; float* Pb;
    if (blockIdx.y == 0) { off = offF; list = listF; Wa = WaF; Pb = PbF; }
    else                 { off = offR; list = listR; Wa = WaR; Pb = PbR; }
    int lane = threadIdx.x & 63;
    int l2 = (lane < 48) ? lane : 47;          // idle lanes get harmless addresses
    bool act = lane < 48;
    // preload 64 weights into registers (static indices -> VGPRs)
    float wr[64];
#pragma unroll
    for (int j = 0; j < 32; ++j) {
        float2 w = *(const float2*)(Wa + j * 96 + 2 * l2);
        wr[2 * j] = w.x; wr[2 * j + 1] = w.y;
    }
    int wid = (blockIdx.x * 256 + threadIdx.x) >> 6;
    int nwaves = gridDim.x * 4;
    for (int n = wid; n < N; n += nwaves) {
        long base = (long)n * 96 + 2 * l2;
        float sx = 0.f, sy = 0.f;
        if (act) { float2 s = *(const float2*)(Pb + base); sx = s.x; sy = s.y; }  // dst proj + b1
        float a0 = 0.f, a1 = 0.f;
        int beg = off[n], end = off[n + 1];
        for (int i = beg; i < end; ++i) {
            int src = __builtin_amdgcn_readfirstlane(list[i]);
            const unsigned* hp = (const unsigned*)(hbf + (long)src * 32);  // uniform -> s_load
            float acc0 = 0.f, acc1 = 0.f;
#pragma unroll
            for (int j = 0; j < 16; ++j) {
                unsigned u = hp[j];
                float hlo = __uint_as_float(u << 16);
                float hhi = __uint_as_float(u & 0xffff0000u);
                acc0 = fmaf(hlo, wr[4 * j], acc0);
                acc1 = fmaf(hlo, wr[4 * j + 1], acc1);
                acc0 = fmaf(hhi, wr[4 * j + 2], acc0);
                acc1 = fmaf(hhi, wr[4 * j + 3], acc1);
            }
            a0 += fmaxf(acc0 + sx, 0.f);
            a1 += fmaxf(acc1 + sy, 0.f);
        }
        if (act) { *(float2*)(Pb + base) = make_float2(a0, a1); }
    }
}

// ---------------- X = aggF@W2 + aggR@rW2 + degF*b2 + degR*rb2 (fused KI=192) ----------------
__global__ void __launch_bounds__(256) x_gemm(
    const float* __restrict__ AF, const float* __restrict__ AR,
    const float* __restrict__ W2, const float* __restrict__ rW2,
    const float* __restrict__ b2, const float* __restrict__ rb2,
    const int* __restrict__ offF, const int* __restrict__ offR,
    float* __restrict__ X, int N)
{
    __shared__ float tile[64][193];
    int n0 = blockIdx.x * 64, tid = threadIdx.x;
    for (int idx = tid; idx < 64 * 96; idx += 256) {
        int r = idx / 96, c = idx % 96;
        int n = n0 + r;
        tile[r][c] = (n < N) ? AF[(long)n * 96 + c] : 0.f;
        tile[r][96 + c] = (n < N) ? AR[(long)n * 96 + c] : 0.f;
    }
    __syncthreads();
    int lane = tid & 63, w = tid >> 6;
    float acc[24];
#pragma unroll
    for (int c = 0; c < 24; ++c) acc[c] = 0.f;
    const float* WpF = W2 + w * 24;
    const float* WpR = rW2 + w * 24;
#pragma unroll 4
    for (int j = 0; j < 96; ++j) {
        float a = tile[lane][j];
#pragma unroll
        for (int c = 0; c < 24; ++c) acc[c] = fmaf(a, WpF[j * 96 + c], acc[c]);
    }
#pragma unroll 4
    for (int j = 0; j < 96; ++j) {
        float a = tile[lane][96 + j];
#pragma unroll
        for (int c = 0; c < 24; ++c) acc[c] = fmaf(a, WpR[j * 96 + c], acc[c]);
    }
    int n = n0 + lane;
    if (n >= N) return;
    float dF = (float)(offF[n + 1] - offF[n]);
    float dR = (float)(offR[n + 1] - offR[n]);
    float* outp = X + (long)n * 96 + w * 24;
#pragma unroll
    for (int c = 0; c < 24; ++c)
        outp[c] = acc[c] + dF * b2[w * 24 + c] + dR * rb2[w * 24 + c];
}

// ---------------- fused GRU (GI/GH stay in registers), writes h fp32 + bf16 ----------------
__global__ void __launch_bounds__(256) gru_fused(
    const float* __restrict__ X, const float* __restrict__ h,
    const float* __restrict__ WihT, const float* __restrict__ WhhT,
    const float* __restrict__ bih, const float* __restrict__ bhh,
    float* __restrict__ hout, unsigned short* __restrict__ hbf, int N)
{
    __shared__ float xt[64][97];
    __shared__ float ht[64][33];
    int n0 = blockIdx.x * 64, tid = threadIdx.x;
    for (int idx = tid; idx < 64 * 96; idx += 256) {
        int r = idx / 96, c = idx % 96;
        int n = n0 + r;
        xt[r][c] = (n < N) ? X[(long)n * 96 + c] : 0.f;
    }
    for (int idx = tid; idx < 64 * 32; idx += 256) {
        int r = idx >> 5, c = idx & 31;
        int n = n0 + r;
        ht[r][c] = (n < N) ? h[(long)n * 32 + c] : 0.f;
    }
    __syncthreads();
    int lane = tid & 63, w = tid >> 6;
    int kb = w * 8;
    float ir[8], iz[8], in_[8], hr[8], hz[8], hn[8];
#pragma unroll
    for (int i = 0; i < 8; ++i) { ir[i] = iz[i] = in_[i] = hr[i] = hz[i] = hn[i] = 0.f; }
#pragma unroll 4
    for (int j = 0; j < 96; ++j) {
        float a = xt[lane][j];
        const float* Wr = WihT + j * 96;
#pragma unroll
        for (int i = 0; i < 8; ++i) {
            ir[i] = fmaf(a, Wr[kb + i], ir[i]);
            iz[i] = fmaf(a, Wr[32 + kb + i], iz[i]);
            in_[i] = fmaf(a, Wr[64 + kb + i], in_[i]);
        }
    }
#pragma unroll 4
    for (int j = 0; j < 32; ++j) {
        float b = ht[lane][j];
        const float* Wr = WhhT + j * 96;
#pragma unroll
        for (int i = 0; i < 8; ++i) {
            hr[i] = fmaf(b, Wr[kb + i], hr[i]);
            hz[i] = fmaf(b, Wr[32 + kb + i], hz[i]);
            hn[i] = fmaf(b, Wr[64 + kb + i], hn[i]);
        }
    }
    __syncthreads();
#pragma unroll
    for (int i = 0; i < 8; ++i) {
        int k = kb + i;
        float r = 1.f / (1.f + __expf(-(ir[i] + bih[k] + hr[i] + bhh[k])));
        float z = 1.f / (1.f + __expf(-(iz[i] + bih[32 + k] + hz[i] + bhh[32 + k])));
        float nn = tanhf(in_[i] + bih[64 + k] + r * (hn[i] + bhh[64 + k]));
        xt[lane][k] = (1.f - z) * nn + z * ht[lane][k];
    }
    __syncthreads();
    for (int idx = tid; idx < 64 * 32; idx += 256) {
        int r = idx >> 5, c = idx & 31;
        int n = n0 + r;
        if (n < N) {
            float v = xt[r][c];
            hout[(long)n * 32 + c] = v;
            hbf[(long)n * 32 + c] = f2bf(v);
        }
    }
}

// ---------------- graph aggregator ----------------
__global__ void graph_agg(const float* __restrict__ h, const float* __restrict__ W1,
                          const float* __restrict__ b1, const int* __restrict__ gidx,
                          float* __restrict__ gs, int N, int chunk) {
    int k = threadIdx.x;  // 128
    int n_start = blockIdx.x * chunk;
    if (n_start >= N) return;
    int n_end = min(n_start + chunk, N);
    float acc = 0.f;
    int cur = gidx[n_start];
    for (int n = n_start; n < n_end; ++n) {
        int g = gidx[n];
        if (g != cur) { atomicAdd(&gs[cur * 128 + k], acc); acc = 0.f; cur = g; }
        float g1 = b1[k], g2 = b1[128 + k];
#pragma unroll 8
        for (int j = 0; j < 32; ++j) {
            float hv = h[(long)n * 32 + j];
            g1 = fmaf(hv, W1[j * 256 + k], g1);
            g2 = fmaf(hv, W1[j * 256 + 128 + k], g2);
        }
        acc += (1.f / (1.f + __expf(-g1))) * g2;
    }
    atomicAdd(&gs[cur * 128 + k], acc);
}

__global__ void final_gemm(const float* __restrict__ gs, const float* __restrict__ W,
                           const float* __restrict__ b, float* __restrict__ out) {
    int g = blockIdx.x, k = threadIdx.x;
    float a = b[k];
#pragma unroll 8
    for (int j = 0; j < 128; ++j) a = fmaf(gs[g * 128 + j], W[j * 128 + k], a);
    out[g * 128 + k] = a;
}

extern "C" void kernel_launch(void* const* d_in, const int* in_sizes, int n_in,
                              void* d_out, int out_size, void* d_ws, size_t ws_size,
                              hipStream_t stream) {
    const float* node_features = (const float*)d_in[0];
    const float* enc_W  = (const float*)d_in[1];
    const float* enc_b  = (const float*)d_in[2];
    const float* msg_W1 = (const float*)d_in[3];
    const float* msg_b1 = (const float*)d_in[4];
    const float* msg_W2 = (const float*)d_in[5];
    const float* msg_b2 = (const float*)d_in[6];
    const float* rmsg_W1 = (const float*)d_in[7];
    const float* rmsg_b1 = (const float*)d_in[8];
    const float* rmsg_W2 = (const float*)d_in[9];
    const float* rmsg_b2 = (const float*)d_in[10];
    const float* gru_Wih = (const float*)d_in[11];
    const float* gru_Whh = (const float*)d_in[12];
    const float* gru_bih = (const float*)d_in[13];
    const float* gru_bhh = (const float*)d_in[14];
    const float* agg_W1 = (const float*)d_in[15];
    const float* agg_b1 = (const float*)d_in[16];
    const float* agg_W2 = (const float*)d_in[17];
    const float* agg_b2 = (const float*)d_in[18];
    const int* from_idx = (const int*)d_in[19];
    const int* to_idx   = (const int*)d_in[20];
    const int* graph_idx = (const int*)d_in[21];

    const int N = in_sizes[0] / 32;
    const int E = in_sizes[19];
    const int NG = out_size / 128;
    float* out = (float*)d_out;

    char* ws = (char*)d_ws;
    auto alloc = [&](size_t b) { void* p = (void*)ws; ws += (b + 255) & ~(size_t)255; return p; };
    int* cnt_to   = (int*)alloc((size_t)N * 4);
    int* cnt_from = (int*)alloc((size_t)N * 4);
    int* off_to   = (int*)alloc((size_t)(N + 1) * 4);
    int* off_from = (int*)alloc((size_t)(N + 1) * 4);
    int* list_to  = (int*)alloc((size_t)E * 4);
    int* list_from= (int*)alloc((size_t)E * 4);
    float* h0  = (float*)alloc((size_t)N * 32 * 4);
    float* h1  = (float*)alloc((size_t)N * 32 * 4);
    unsigned short* hbf = (unsigned short*)alloc((size_t)N * 32 * 2);
    float* PFb = (float*)alloc((size_t)N * 96 * 4);
    float* PRb = (float*)alloc((size_t)N * 96 * 4);
    float* X   = (float*)alloc((size_t)N * 96 * 4);
    float* WihT = (float*)alloc((size_t)3 * 96 * 96 * 4);
    float* WhhT = (float*)alloc((size_t)3 * 32 * 96 * 4);
    float* gs   = (float*)alloc((size_t)NG * 128 * 4);
    // rank arrays alias P-buffers (dead before proj writes them)
    int* rank_to   = (int*)PFb;
    int* rank_from = (int*)PRb;

    hipMemsetAsync(cnt_to, 0, (size_t)N * 4, stream);
    hipMemsetAsync(cnt_from, 0, (size_t)N * 4, stream);
    hipMemsetAsync(gs, 0, (size_t)NG * 128 * 4, stream);

    int gE = (E + 255) / 256;
    count_rank_kernel<<<gE, 256, 0, stream>>>(from_idx, to_idx, cnt_to, cnt_from, rank_to, rank_from, E);
    scan2_kernel<<<2, 1024, 0, stream>>>(cnt_to, off_to, cnt_from, off_from, N);
    fill_kernel<<<gE, 256, 0, stream>>>(from_idx, to_idx, off_to, off_from, rank_to, rank_from,
                                        list_to, list_from, E);

    transpose_all<<<(3 * 96 * 96 + 3 * 32 * 96 + 255) / 256, 256, 0, stream>>>(gru_Wih, gru_Whh, WihT, WhhT);

    int gN64 = (N + 63) / 64;
    enc_gemm<<<gN64, 256, 0, stream>>>(node_features, enc_W, enc_b, h0, hbf, N);

    float* hcur = h0; float* hnext = h1;
    dim3 gProj(gN64, 2), gAgg(2048, 2);
    for (int l = 0; l < 3; ++l) {
        proj_kernel<<<gProj, 256, 0, stream>>>(hcur, msg_W1 + l * 6144, msg_b1 + l * 96,
                                               rmsg_W1 + l * 6144, rmsg_b1 + l * 96, PFb, PRb, N);
        agg_fused<<<gAgg, 256, 0, stream>>>(off_to, list_to, off_from, list_from, hbf,
                                            msg_W1 + l * 6144, rmsg_W1 + l * 6144, PFb, PRb, N);
        x_gemm<<<gN64, 256, 0, stream>>>(PFb, PRb, msg_W2 + l * 9216, rmsg_W2 + l * 9216,
                                         msg_b2 + l * 96, rmsg_b2 + l * 96, off_to, off_from, X, N);
        gru_fused<<<gN64, 256, 0, stream>>>(X, hcur, WihT + l * 9216, WhhT + l * 3072,
                                            gru_bih + l * 96, gru_bhh + l * 96, hnext, hbf, N);
        float* t = hcur; hcur = hnext; hnext = t;
    }

    graph_agg<<<(N + 63) / 64, 128, 0, stream>>>(hcur, agg_W1, agg_b1, graph_idx, gs, N, 64);
    final_gemm<<<NG, 128, 0, stream>>>(gs, agg_W2, agg_b2, out);
}

// Round 4
// 1763.290 us; speedup vs baseline: 1.1221x; 1.1221x over previous
//
#include <hip/hip_runtime.h>

__device__ inline unsigned short f2bf(float f) {
    unsigned u = __float_as_uint(f);
    unsigned r = (u + 0x7fffu + ((u >> 16) & 1u)) >> 16;   // round-nearest-even
    return (unsigned short)r;
}

// ---------------- CSR build (rank captured in count pass; fill is atomic-free) ----------------
__global__ void count_rank_kernel(const int* __restrict__ from_idx, const int* __restrict__ to_idx,
                                  int* __restrict__ cnt_to, int* __restrict__ cnt_from,
                                  int* __restrict__ rank_to, int* __restrict__ rank_from, int E) {
    int e = blockIdx.x * blockDim.x + threadIdx.x;
    if (e >= E) return;
    int f = from_idx[e], t = to_idx[e];
    rank_to[e] = atomicAdd(&cnt_to[t], 1);
    rank_from[e] = atomicAdd(&cnt_from[f], 1);
}

__global__ void scan2_kernel(const int* __restrict__ cnt_to, int* __restrict__ off_to,
                             const int* __restrict__ cnt_from, int* __restrict__ off_from, int n) {
    const int* cnt = blockIdx.x ? cnt_from : cnt_to;
    int* off = blockIdx.x ? off_from : off_to;
    __shared__ int part[1024];
    int tid = threadIdx.x;
    int chunk = (n + 1023) >> 10;
    int beg = tid * chunk, end = min(beg + chunk, n);
    int s = 0;
    for (int i = beg; i < end; ++i) s += cnt[i];
    part[tid] = s;
    __syncthreads();
    for (int d = 1; d < 1024; d <<= 1) {
        int v = part[tid];
        int add = (tid >= d) ? part[tid - d] : 0;
        __syncthreads();
        part[tid] = v + add;
        __syncthreads();
    }
    int base = part[tid] - s;
    for (int i = beg; i < end; ++i) { off[i] = base; base += cnt[i]; }
    if (tid == 1023) off[n] = part[1023];
}

__global__ void fill_kernel(const int* __restrict__ from_idx, const int* __restrict__ to_idx,
                            const int* __restrict__ off_to, const int* __restrict__ off_from,
                            const int* __restrict__ rank_to, const int* __restrict__ rank_from,
                            int* __restrict__ list_to, int* __restrict__ list_from, int E) {
    int e = blockIdx.x * blockDim.x + threadIdx.x;
    if (e >= E) return;
    int f = from_idx[e], t = to_idx[e];
    list_to[off_to[t] + rank_to[e]] = f;
    list_from[off_from[f] + rank_from[e]] = t;
}

// ---------------- weight transposes (GRU uses x @ W.T) ----------------
__global__ void transpose_all(const float* __restrict__ Wih, const float* __restrict__ Whh,
                              float* __restrict__ WihT, float* __restrict__ WhhT) {
    int idx = blockIdx.x * 256 + threadIdx.x;
    if (idx < 3 * 96 * 96) {
        int l = idx / 9216, r = idx % 9216;
        int j = r / 96, k = r % 96;
        WihT[idx] = Wih[l * 9216 + k * 96 + j];
    } else if (idx < 3 * 96 * 96 + 3 * 32 * 96) {
        int i2 = idx - 3 * 96 * 96;
        int l = i2 / 3072, r = i2 % 3072;
        int j = r / 96, k = r % 96;
        WhhT[i2] = Whh[l * 3072 + k * 32 + j];
    }
}

// ---------------- encoder: h = IN@W + b ----------------
__global__ void __launch_bounds__(256) enc_gemm(const float* __restrict__ IN,
                                                const float* __restrict__ W, const float* __restrict__ bias,
                                                float* __restrict__ OUT, int N) {
    __shared__ float tile[64][33];
    int n0 = blockIdx.x * 64, tid = threadIdx.x;
    for (int idx = tid; idx < 64 * 32; idx += 256) {
        int r = idx >> 5, c = idx & 31;
        int n = n0 + r;
        tile[r][c] = (n < N) ? IN[(long)n * 32 + c] : 0.f;
    }
    __syncthreads();
    int lane = tid & 63, w = tid >> 6;
    float acc[8] = {0};
    const float* Wp = W + w * 8;
#pragma unroll
    for (int j = 0; j < 32; ++j) {
        float a = tile[lane][j];
#pragma unroll
        for (int c = 0; c < 8; ++c) acc[c] = fmaf(a, Wp[j * 32 + c], acc[c]);
    }
    int n = n0 + lane;
    if (n >= N) return;
    float* outp = OUT + (long)n * 32 + w * 8;
#pragma unroll
    for (int c = 0; c < 8; ++c) outp[c] = acc[c] + bias[w * 8 + c];
}

// ---------------- projections: Pa = h@W1[:32] (bf16 packed), Pb = h@W1[32:] + b1 (fp32); y: fwd/rev ----
__global__ void __launch_bounds__(256) proj_kernel(
    const float* __restrict__ h,
    const float* __restrict__ W1f, const float* __restrict__ b1f,
    const float* __restrict__ W1r, const float* __restrict__ b1r,
    unsigned* __restrict__ PaFu, float* __restrict__ PbF,
    unsigned* __restrict__ PaRu, float* __restrict__ PbR, int N)
{
    const float* W1 = blockIdx.y ? W1r : W1f;
    const float* b1 = blockIdx.y ? b1r : b1f;
    unsigned* PaU = blockIdx.y ? PaRu : PaFu;
    float* Pb = blockIdx.y ? PbR : PbF;
    __shared__ float tile[64][33];
    int n0 = blockIdx.x * 64, tid = threadIdx.x;
    for (int idx = tid; idx < 64 * 32; idx += 256) {
        int r = idx >> 5, c = idx & 31;
        int n = n0 + r;
        tile[r][c] = (n < N) ? h[(long)n * 32 + c] : 0.f;
    }
    __syncthreads();
    int lane = tid & 63, w = tid >> 6;
    int c0 = w * 48;                            // waves 0,1 -> Pa (src-half); 2,3 -> Pb (dst-half)
    const float* Wp = (c0 < 96) ? (W1 + c0) : (W1 + 32 * 96 + (c0 - 96));
    float acc[48];
#pragma unroll
    for (int c = 0; c < 48; ++c) acc[c] = 0.f;
#pragma unroll 4
    for (int j = 0; j < 32; ++j) {
        float a = tile[lane][j];
#pragma unroll
        for (int c = 0; c < 48; ++c) acc[c] = fmaf(a, Wp[j * 96 + c], acc[c]);
    }
    int n = n0 + lane;
    if (n >= N) return;
    if (c0 < 96) {
        unsigned* pap = PaU + (long)n * 48 + (c0 >> 1);
#pragma unroll
        for (int c = 0; c < 24; ++c)
            pap[c] = (unsigned)f2bf(acc[2 * c]) | ((unsigned)f2bf(acc[2 * c + 1]) << 16);
    } else {
        float* outp = Pb + (long)n * 96 + (c0 - 96);
#pragma unroll
        for (int c = 0; c < 48; ++c) outp[c] = acc[c] + b1[c0 - 96 + c];
    }
}

// ---------------- edge aggregation: gather packed-bf16 Pa rows (192 B), relu, accumulate ----------------
__global__ void __launch_bounds__(256) agg_bf16(
    const int* __restrict__ offF, const int* __restrict__ listF,
    const int* __restrict__ offR, const int* __restrict__ listR,
    const unsigned* __restrict__ PaF, const unsigned* __restrict__ PaR,
    float* PbF, float* PbR, int N)
{
    const int* off; const int* list; const unsigned* Pa; float* Pb;
    if (blockIdx.y == 0) { off = offF; list = listF; Pa = PaF; Pb = PbF; }
    else                 { off = offR; list = listR; Pa = PaR; Pb = PbR; }
    int n = (blockIdx.x * 256 + threadIdx.x) >> 6;
    int lane = threadIdx.x & 63;
    if (n >= N) return;
    int li = (lane < 48) ? lane : 47;           // idle lanes duplicate col 47 (same line, free)
    bool act = lane < 48;
    long pbase = (long)n * 96 + 2 * li;
    float sx = 0.f, sy = 0.f;
    if (act) { float2 s = *(const float2*)(Pb + pbase); sx = s.x; sy = s.y; }  // dst proj + b1
    float a0 = 0.f, a1 = 0.f;
    int beg = off[n], end = off[n + 1];
    for (int i = beg; i < end; ++i) {
        int src = __builtin_amdgcn_readfirstlane(list[i]);
        unsigned u = Pa[(long)src * 48 + li];   // scalar base + lane*4 -> coalesced 192 B
        float lo = __uint_as_float(u << 16);
        float hi = __uint_as_float(u & 0xffff0000u);
        a0 += fmaxf(lo + sx, 0.f);
        a1 += fmaxf(hi + sy, 0.f);
    }
    if (act) { *(float2*)(Pb + pbase) = make_float2(a0, a1); }
}

// ---------------- fused X + GRU: X = AF@W2 + AR@rW2 + deg biases (kept in LDS), then GRU ----------------
__global__ void __launch_bounds__(256) xgru_kernel(
    const float* __restrict__ AF, const float* __restrict__ AR,
    const float* __restrict__ W2, const float* __restrict__ rW2,
    const float* __restrict__ b2, const float* __restrict__ rb2,
    const int* __restrict__ offF, const int* __restrict__ offR,
    const float* __restrict__ h,
    const float* __restrict__ WihT, const float* __restrict__ WhhT,
    const float* __restrict__ bih, const float* __restrict__ bhh,
    float* __restrict__ hout, int N)
{
    __shared__ float buf[64 * 193];             // stage AF|AR (stride 193), then reused as X (stride 97)
    __shared__ float ht[64][33];
    int n0 = blockIdx.x * 64, tid = threadIdx.x;
    for (int idx = tid; idx < 64 * 96; idx += 256) {
        int r = idx / 96, c = idx % 96;
        int n = n0 + r;
        buf[r * 193 + c] = (n < N) ? AF[(long)n * 96 + c] : 0.f;
        buf[r * 193 + 96 + c] = (n < N) ? AR[(long)n * 96 + c] : 0.f;
    }
    for (int idx = tid; idx < 64 * 32; idx += 256) {
        int r = idx >> 5, c = idx & 31;
        int n = n0 + r;
        ht[r][c] = (n < N) ? h[(long)n * 32 + c] : 0.f;
    }
    __syncthreads();
    int lane = tid & 63, w = tid >> 6;
    float acc[24];
#pragma unroll
    for (int c = 0; c < 24; ++c) acc[c] = 0.f;
    const float* WpF = W2 + w * 24;
    const float* WpR = rW2 + w * 24;
#pragma unroll 4
    for (int j = 0; j < 96; ++j) {
        float a = buf[lane * 193 + j];
#pragma unroll
        for (int c = 0; c < 24; ++c) acc[c] = fmaf(a, WpF[j * 96 + c], acc[c]);
    }
#pragma unroll 4
    for (int j = 0; j < 96; ++j) {
        float a = buf[lane * 193 + 96 + j];
#pragma unroll
        for (int c = 0; c < 24; ++c) acc[c] = fmaf(a, WpR[j * 96 + c], acc[c]);
    }
    int nb = min(n0 + lane, N - 1);
    float dF = (float)(offF[nb + 1] - offF[nb]);
    float dR = (float)(offR[nb + 1] - offR[nb]);
    __syncthreads();                            // all stride-193 reads done; repurpose buf as X (stride 97)
#pragma unroll
    for (int c = 0; c < 24; ++c)
        buf[lane * 97 + w * 24 + c] = acc[c] + dF * b2[w * 24 + c] + dR * rb2[w * 24 + c];
    __syncthreads();
    // ---- GRU ----
    int kb = w * 8;
    float ir[8], iz[8], in_[8], hr[8], hz[8], hn[8];
#pragma unroll
    for (int i = 0; i < 8; ++i) { ir[i] = iz[i] = in_[i] = hr[i] = hz[i] = hn[i] = 0.f; }
#pragma unroll 4
    for (int j = 0; j < 96; ++j) {
        float a = buf[lane * 97 + j];
        const float* Wr = WihT + j * 96;
#pragma unroll
        for (int i = 0; i < 8; ++i) {
            ir[i] = fmaf(a, Wr[kb + i], ir[i]);
            iz[i] = fmaf(a, Wr[32 + kb + i], iz[i]);
            in_[i] = fmaf(a, Wr[64 + kb + i], in_[i]);
        }
    }
#pragma unroll 4
    for (int j = 0; j < 32; ++j) {
        float b = ht[lane][j];
        const float* Wr = WhhT + j * 96;
#pragma unroll
        for (int i = 0; i < 8; ++i) {
            hr[i] = fmaf(b, Wr[kb + i], hr[i]);
            hz[i] = fmaf(b, Wr[32 + kb + i], hz[i]);
            hn[i] = fmaf(b, Wr[64 + kb + i], hn[i]);
        }
    }
    __syncthreads();                            // all X reads done before overwriting buf rows
#pragma unroll
    for (int i = 0; i < 8; ++i) {
        int k = kb + i;
        float r = 1.f / (1.f + __expf(-(ir[i] + bih[k] + hr[i] + bhh[k])));
        float z = 1.f / (1.f + __expf(-(iz[i] + bih[32 + k] + hz[i] + bhh[32 + k])));
        float nn = tanhf(in_[i] + bih[64 + k] + r * (hn[i] + bhh[64 + k]));
        buf[lane * 97 + k] = (1.f - z) * nn + z * ht[lane][k];
    }
    __syncthreads();
    for (int idx = tid; idx < 64 * 32; idx += 256) {
        int r = idx >> 5, c = idx & 31;
        int n = n0 + r;
        if (n < N) hout[(long)n * 32 + c] = buf[r * 97 + c];
    }
}

// ---------------- graph aggregator ----------------
__global__ void graph_agg(const float* __restrict__ h, const float* __restrict__ W1,
                          const float* __restrict__ b1, const int* __restrict__ gidx,
                          float* __restrict__ gs, int N, int chunk) {
    int k = threadIdx.x;  // 128
    int n_start = blockIdx.x * chunk;
    if (n_start >= N) return;
    int n_end = min(n_start + chunk, N);
    float acc = 0.f;
    int cur = gidx[n_start];
    for (int n = n_start; n < n_end; ++n) {
        int g = gidx[n];
        if (g != cur) { atomicAdd(&gs[cur * 128 + k], acc); acc = 0.f; cur = g; }
        float g1 = b1[k], g2 = b1[128 + k];
#pragma unroll 8
        for (int j = 0; j < 32; ++j) {
            float hv = h[(long)n * 32 + j];
            g1 = fmaf(hv, W1[j * 256 + k], g1);
            g2 = fmaf(hv, W1[j * 256 + 128 + k], g2);
        }
        acc += (1.f / (1.f + __expf(-g1))) * g2;
    }
    atomicAdd(&gs[cur * 128 + k], acc);
}

__global__ void final_gemm(const float* __restrict__ gs, const float* __restrict__ W,
                           const float* __restrict__ b, float* __restrict__ out) {
    int g = blockIdx.x, k = threadIdx.x;
    float a = b[k];
#pragma unroll 8
    for (int j = 0; j < 128; ++j) a = fmaf(gs[g * 128 + j], W[j * 128 + k], a);
    out[g * 128 + k] = a;
}

extern "C" void kernel_launch(void* const* d_in, const int* in_sizes, int n_in,
                              void* d_out, int out_size, void* d_ws, size_t ws_size,
                              hipStream_t stream) {
    const float* node_features = (const float*)d_in[0];
    const float* enc_W  = (const float*)d_in[1];
    const float* enc_b  = (const float*)d_in[2];
    const float* msg_W1 = (const float*)d_in[3];
    const float* msg_b1 = (const float*)d_in[4];
    const float* msg_W2 = (const float*)d_in[5];
    const float* msg_b2 = (const float*)d_in[6];
    const float* rmsg_W1 = (const float*)d_in[7];
    const float* rmsg_b1 = (const float*)d_in[8];
    const float* rmsg_W2 = (const float*)d_in[9];
    const float* rmsg_b2 = (const float*)d_in[10];
    const float* gru_Wih = (const float*)d_in[11];
    const float* gru_Whh = (const float*)d_in[12];
    const float* gru_bih = (const float*)d_in[13];
    const float* gru_bhh = (const float*)d_in[14];
    const float* agg_W1 = (const float*)d_in[15];
    const float* agg_b1 = (const float*)d_in[16];
    const float* agg_W2 = (const float*)d_in[17];
    const float* agg_b2 = (const float*)d_in[18];
    const int* from_idx = (const int*)d_in[19];
    const int* to_idx   = (const int*)d_in[20];
    const int* graph_idx = (const int*)d_in[21];

    const int N = in_sizes[0] / 32;
    const int E = in_sizes[19];
    const int NG = out_size / 128;
    float* out = (float*)d_out;

    char* ws = (char*)d_ws;
    auto alloc = [&](size_t b) { void* p = (void*)ws; ws += (b + 255) & ~(size_t)255; return p; };
    int* cnt_to   = (int*)alloc((size_t)N * 4);
    int* cnt_from = (int*)alloc((size_t)N * 4);
    int* off_to   = (int*)alloc((size_t)(N + 1) * 4);
    int* off_from = (int*)alloc((size_t)(N + 1) * 4);
    int* list_to  = (int*)alloc((size_t)E * 4);
    int* list_from= (int*)alloc((size_t)E * 4);
    float* h0  = (float*)alloc((size_t)N * 32 * 4);
    float* h1  = (float*)alloc((size_t)N * 32 * 4);
    unsigned* PaF = (unsigned*)alloc((size_t)N * 48 * 4);
    unsigned* PaR = (unsigned*)alloc((size_t)N * 48 * 4);
    float* PbF = (float*)alloc((size_t)N * 96 * 4);
    float* PbR = (float*)alloc((size_t)N * 96 * 4);
    float* WihT = (float*)alloc((size_t)3 * 96 * 96 * 4);
    float* WhhT = (float*)alloc((size_t)3 * 32 * 96 * 4);
    float* gs   = (float*)alloc((size_t)NG * 128 * 4);
    // rank arrays alias Pb buffers (dead before proj writes them)
    int* rank_to   = (int*)PbF;
    int* rank_from = (int*)PbR;

    hipMemsetAsync(cnt_to, 0, (size_t)N * 4, stream);
    hipMemsetAsync(cnt_from, 0, (size_t)N * 4, stream);
    hipMemsetAsync(gs, 0, (size_t)NG * 128 * 4, stream);

    int gE = (E + 255) / 256;
    count_rank_kernel<<<gE, 256, 0, stream>>>(from_idx, to_idx, cnt_to, cnt_from, rank_to, rank_from, E);
    scan2_kernel<<<2, 1024, 0, stream>>>(cnt_to, off_to, cnt_from, off_from, N);
    fill_kernel<<<gE, 256, 0, stream>>>(from_idx, to_idx, off_to, off_from, rank_to, rank_from,
                                        list_to, list_from, E);

    transpose_all<<<(3 * 96 * 96 + 3 * 32 * 96 + 255) / 256, 256, 0, stream>>>(gru_Wih, gru_Whh, WihT, WhhT);

    int gN64 = (N + 63) / 64;
    enc_gemm<<<gN64, 256, 0, stream>>>(node_features, enc_W, enc_b, h0, N);

    float* hcur = h0; float* hnext = h1;
    dim3 gProj(gN64, 2), gAgg((N + 3) / 4, 2);
    for (int l = 0; l < 3; ++l) {
        proj_kernel<<<gProj, 256, 0, stream>>>(hcur, msg_W1 + l * 6144, msg_b1 + l * 96,
                                               rmsg_W1 + l * 6144, rmsg_b1 + l * 96,
                                               PaF, PbF, PaR, PbR, N);
        agg_bf16<<<gAgg, 256, 0, stream>>>(off_to, list_to, off_from, list_from,
                                           PaF, PaR, PbF, PbR, N);
        xgru_kernel<<<gN64, 256, 0, stream>>>(PbF, PbR, msg_W2 + l * 9216, rmsg_W2 + l * 9216,
                                              msg_b2 + l * 96, rmsg_b2 + l * 96, off_to, off_from,
                                              hcur, WihT + l * 9216, WhhT + l * 3072,
                                              gru_bih + l * 96, gru_bhh + l * 96, hnext, N);
        float* t = hcur; hcur = hnext; hnext = t;
    }

    graph_agg<<<(N + 63) / 64, 128, 0, stream>>>(hcur, agg_W1, agg_b1, graph_idx, gs, N, 64);
    final_gemm<<<NG, 128, 0, stream>>>(gs, agg_W2, agg_b2, out);
}

// Round 5
// 1686.994 us; speedup vs baseline: 1.1728x; 1.0452x over previous
//
#include <hip/hip_runtime.h>

__device__ inline unsigned short f2bf(float f) {
    unsigned u = __float_as_uint(f);
    unsigned r = (u + 0x7fffu + ((u >> 16) & 1u)) >> 16;   // round-nearest-even
    return (unsigned short)r;
}

// ---------------- CSR build (rank captured in count pass; fill is atomic-free) ----------------
__global__ void count_rank_kernel(const int* __restrict__ from_idx, const int* __restrict__ to_idx,
                                  int* __restrict__ cnt_to, int* __restrict__ cnt_from,
                                  int* __restrict__ rank_to, int* __restrict__ rank_from, int E) {
    int e = blockIdx.x * blockDim.x + threadIdx.x;
    if (e >= E) return;
    int f = from_idx[e], t = to_idx[e];
    rank_to[e] = atomicAdd(&cnt_to[t], 1);
    rank_from[e] = atomicAdd(&cnt_from[f], 1);
}

__global__ void scan2_kernel(const int* __restrict__ cnt_to, int* __restrict__ off_to,
                             const int* __restrict__ cnt_from, int* __restrict__ off_from, int n) {
    const int* cnt = blockIdx.x ? cnt_from : cnt_to;
    int* off = blockIdx.x ? off_from : off_to;
    __shared__ int part[1024];
    int tid = threadIdx.x;
    int chunk = (n + 1023) >> 10;
    int beg = tid * chunk, end = min(beg + chunk, n);
    int s = 0;
    for (int i = beg; i < end; ++i) s += cnt[i];
    part[tid] = s;
    __syncthreads();
    for (int d = 1; d < 1024; d <<= 1) {
        int v = part[tid];
        int add = (tid >= d) ? part[tid - d] : 0;
        __syncthreads();
        part[tid] = v + add;
        __syncthreads();
    }
    int base = part[tid] - s;
    for (int i = beg; i < end; ++i) { off[i] = base; base += cnt[i]; }
    if (tid == 1023) off[n] = part[1023];
}

__global__ void fill_kernel(const int* __restrict__ from_idx, const int* __restrict__ to_idx,
                            const int* __restrict__ off_to, const int* __restrict__ off_from,
                            const int* __restrict__ rank_to, const int* __restrict__ rank_from,
                            int* __restrict__ list_to, int* __restrict__ list_from, int E) {
    int e = blockIdx.x * blockDim.x + threadIdx.x;
    if (e >= E) return;
    int f = from_idx[e], t = to_idx[e];
    list_to[off_to[t] + rank_to[e]] = f;
    list_from[off_from[f] + rank_from[e]] = t;
}

// ---------------- weight transposes (GRU uses x @ W.T) ----------------
__global__ void transpose_all(const float* __restrict__ Wih, const float* __restrict__ Whh,
                              float* __restrict__ WihT, float* __restrict__ WhhT) {
    int idx = blockIdx.x * 256 + threadIdx.x;
    if (idx < 3 * 96 * 96) {
        int l = idx / 9216, r = idx % 9216;
        int j = r / 96, k = r % 96;
        WihT[idx] = Wih[l * 9216 + k * 96 + j];
    } else if (idx < 3 * 96 * 96 + 3 * 32 * 96) {
        int i2 = idx - 3 * 96 * 96;
        int l = i2 / 3072, r = i2 % 3072;
        int j = r / 96, k = r % 96;
        WhhT[i2] = Whh[l * 3072 + k * 32 + j];
    }
}

// ---------------- encoder: h = IN@W + b ----------------
__global__ void __launch_bounds__(256) enc_gemm(const float* __restrict__ IN,
                                                const float* __restrict__ W, const float* __restrict__ bias,
                                                float* __restrict__ OUT, int N) {
    __shared__ float tile[64][36];
    int n0 = blockIdx.x * 64, tid = threadIdx.x;
    for (int idx = tid; idx < 64 * 32; idx += 256) {
        int r = idx >> 5, c = idx & 31;
        int n = n0 + r;
        tile[r][c] = (n < N) ? IN[(long)n * 32 + c] : 0.f;
    }
    __syncthreads();
    int lane = tid & 63, w = tid >> 6;
    float a[32];
#pragma unroll
    for (int j = 0; j < 32; ++j) a[j] = tile[lane][j];
    float acc[8] = {0};
    const float* Wp = W + w * 8;
#pragma unroll
    for (int j = 0; j < 32; ++j)
#pragma unroll
        for (int c = 0; c < 8; ++c) acc[c] = fmaf(a[j], Wp[j * 32 + c], acc[c]);
    int n = n0 + lane;
    if (n >= N) return;
    float* outp = OUT + (long)n * 32 + w * 8;
#pragma unroll
    for (int c = 0; c < 8; ++c) outp[c] = acc[c] + bias[w * 8 + c];
}

// ---------------- projections: Pa = h@W1[:32] (bf16 packed), Pb = h@W1[32:] + b1 (fp32); y: fwd/rev ----
__global__ void __launch_bounds__(256) proj_kernel(
    const float* __restrict__ h,
    const float* __restrict__ W1f, const float* __restrict__ b1f,
    const float* __restrict__ W1r, const float* __restrict__ b1r,
    unsigned* __restrict__ PaFu, float* __restrict__ PbF,
    unsigned* __restrict__ PaRu, float* __restrict__ PbR, int N)
{
    const float* W1 = blockIdx.y ? W1r : W1f;
    const float* b1 = blockIdx.y ? b1r : b1f;
    unsigned* PaU = blockIdx.y ? PaRu : PaFu;
    float* Pb = blockIdx.y ? PbR : PbF;
    __shared__ float tile[64][36];
    int n0 = blockIdx.x * 64, tid = threadIdx.x;
    for (int idx = tid; idx < 64 * 32; idx += 256) {
        int r = idx >> 5, c = idx & 31;
        int n = n0 + r;
        tile[r][c] = (n < N) ? h[(long)n * 32 + c] : 0.f;
    }
    __syncthreads();
    int lane = tid & 63, w = tid >> 6;
    float a[32];
#pragma unroll
    for (int j = 0; j < 32; ++j) a[j] = tile[lane][j];
    int c0 = w * 48;                            // waves 0,1 -> Pa (src-half); 2,3 -> Pb (dst-half)
    const float* Wp = (c0 < 96) ? (W1 + c0) : (W1 + 32 * 96 + (c0 - 96));
    float acc[48];
#pragma unroll
    for (int c = 0; c < 48; ++c) acc[c] = 0.f;
#pragma unroll
    for (int j = 0; j < 32; ++j)
#pragma unroll
        for (int c = 0; c < 48; ++c) acc[c] = fmaf(a[j], Wp[j * 96 + c], acc[c]);
    int n = n0 + lane;
    if (n >= N) return;
    if (c0 < 96) {
        unsigned* pap = PaU + (long)n * 48 + (c0 >> 1);
#pragma unroll
        for (int c = 0; c < 24; ++c)
            pap[c] = (unsigned)f2bf(acc[2 * c]) | ((unsigned)f2bf(acc[2 * c + 1]) << 16);
    } else {
        float* outp = Pb + (long)n * 96 + (c0 - 96);
#pragma unroll
        for (int c = 0; c < 48; ++c) outp[c] = acc[c] + b1[c0 - 96 + c];
    }
}

// ---------------- edge aggregation: gather packed-bf16 Pa rows (192 B), relu, accumulate ----------------
__global__ void __launch_bounds__(256) agg_bf16(
    const int* __restrict__ offF, const int* __restrict__ listF,
    const int* __restrict__ offR, const int* __restrict__ listR,
    const unsigned* __restrict__ PaF, const unsigned* __restrict__ PaR,
    float* PbF, float* PbR, int N)
{
    const int* off; const int* list; const unsigned* Pa; float* Pb;
    if (blockIdx.y == 0) { off = offF; list = listF; Pa = PaF; Pb = PbF; }
    else                 { off = offR; list = listR; Pa = PaR; Pb = PbR; }
    int n = (blockIdx.x * 256 + threadIdx.x) >> 6;
    int lane = threadIdx.x & 63;
    if (n >= N) return;
    int li = (lane < 48) ? lane : 47;           // idle lanes duplicate col 47 (same line, free)
    bool act = lane < 48;
    long pbase = (long)n * 96 + 2 * li;
    float sx = 0.f, sy = 0.f;
    if (act) { float2 s = *(const float2*)(Pb + pbase); sx = s.x; sy = s.y; }  // dst proj + b1
    float a0 = 0.f, a1 = 0.f;
    int beg = off[n], end = off[n + 1];
    int i = beg;
    for (; i + 4 <= end; i += 4) {              // 4 gathers in flight
        int s0 = __builtin_amdgcn_readfirstlane(list[i]);
        int s1 = __builtin_amdgcn_readfirstlane(list[i + 1]);
        int s2 = __builtin_amdgcn_readfirstlane(list[i + 2]);
        int s3 = __builtin_amdgcn_readfirstlane(list[i + 3]);
        unsigned u0 = Pa[(long)s0 * 48 + li];
        unsigned u1 = Pa[(long)s1 * 48 + li];
        unsigned u2 = Pa[(long)s2 * 48 + li];
        unsigned u3 = Pa[(long)s3 * 48 + li];
        a0 += fmaxf(__uint_as_float(u0 << 16) + sx, 0.f);
        a1 += fmaxf(__uint_as_float(u0 & 0xffff0000u) + sy, 0.f);
        a0 += fmaxf(__uint_as_float(u1 << 16) + sx, 0.f);
        a1 += fmaxf(__uint_as_float(u1 & 0xffff0000u) + sy, 0.f);
        a0 += fmaxf(__uint_as_float(u2 << 16) + sx, 0.f);
        a1 += fmaxf(__uint_as_float(u2 & 0xffff0000u) + sy, 0.f);
        a0 += fmaxf(__uint_as_float(u3 << 16) + sx, 0.f);
        a1 += fmaxf(__uint_as_float(u3 & 0xffff0000u) + sy, 0.f);
    }
    for (; i < end; ++i) {
        int src = __builtin_amdgcn_readfirstlane(list[i]);
        unsigned u = Pa[(long)src * 48 + li];
        a0 += fmaxf(__uint_as_float(u << 16) + sx, 0.f);
        a1 += fmaxf(__uint_as_float(u & 0xffff0000u) + sy, 0.f);
    }
    if (act) { *(float2*)(Pb + pbase) = make_float2(a0, a1); }
}

// ---------------- fused X + GRU, phased staging (LDS 34 KB -> 4 blocks/CU) ----------------
__global__ void __launch_bounds__(256) xgru_kernel(
    const float* __restrict__ AF, const float* __restrict__ AR,
    const float* __restrict__ W2, const float* __restrict__ rW2,
    const float* __restrict__ b2, const float* __restrict__ rb2,
    const int* __restrict__ offF, const int* __restrict__ offR,
    const float* __restrict__ h,
    const float* __restrict__ WihT, const float* __restrict__ WhhT,
    const float* __restrict__ bih, const float* __restrict__ bhh,
    float* __restrict__ hout, int N)
{
    __shared__ float buf[64 * 100];             // AF -> AR -> X (stride 100, 16B-aligned rows)
    __shared__ float ht[64][36];
    int n0 = blockIdx.x * 64, tid = threadIdx.x;
    int lane = tid & 63, w = tid >> 6;

    for (int idx = tid; idx < 64 * 96; idx += 256) {
        int r = idx / 96, c = idx % 96;
        int n = n0 + r;
        buf[r * 100 + c] = (n < N) ? AF[(long)n * 96 + c] : 0.f;
    }
    for (int idx = tid; idx < 64 * 32; idx += 256) {
        int r = idx >> 5, c = idx & 31;
        int n = n0 + r;
        ht[r][c] = (n < N) ? h[(long)n * 32 + c] : 0.f;
    }
    __syncthreads();

    float acc[24];
#pragma unroll
    for (int c = 0; c < 24; ++c) acc[c] = 0.f;
    const float* WpF = W2 + w * 24;
#pragma unroll 2
    for (int jt = 0; jt < 96; jt += 8) {        // register-tile: burst LDS reads, then pure s_load+FMA
        float a[8];
#pragma unroll
        for (int u = 0; u < 8; ++u) a[u] = buf[lane * 100 + jt + u];
#pragma unroll
        for (int u = 0; u < 8; ++u)
#pragma unroll
            for (int c = 0; c < 24; ++c) acc[c] = fmaf(a[u], WpF[(jt + u) * 96 + c], acc[c]);
    }
    __syncthreads();                            // GEMM1 reads done; restage with AR
    for (int idx = tid; idx < 64 * 96; idx += 256) {
        int r = idx / 96, c = idx % 96;
        int n = n0 + r;
        buf[r * 100 + c] = (n < N) ? AR[(long)n * 96 + c] : 0.f;
    }
    __syncthreads();
    const float* WpR = rW2 + w * 24;
#pragma unroll 2
    for (int jt = 0; jt < 96; jt += 8) {
        float a[8];
#pragma unroll
        for (int u = 0; u < 8; ++u) a[u] = buf[lane * 100 + jt + u];
#pragma unroll
        for (int u = 0; u < 8; ++u)
#pragma unroll
            for (int c = 0; c < 24; ++c) acc[c] = fmaf(a[u], WpR[(jt + u) * 96 + c], acc[c]);
    }
    int nb = min(n0 + lane, N - 1);
    float dF = (float)(offF[nb + 1] - offF[nb]);
    float dR = (float)(offR[nb + 1] - offR[nb]);
    __syncthreads();                            // GEMM2 reads done; buf becomes X
#pragma unroll
    for (int c = 0; c < 24; ++c)
        buf[lane * 100 + w * 24 + c] = acc[c] + dF * b2[w * 24 + c] + dR * rb2[w * 24 + c];
    __syncthreads();

    // ---- GRU ----
    int kb = w * 8;
    float ir[8], iz[8], in_[8], hr[8], hz[8], hn[8];
#pragma unroll
    for (int i = 0; i < 8; ++i) { ir[i] = iz[i] = in_[i] = hr[i] = hz[i] = hn[i] = 0.f; }
#pragma unroll 2
    for (int jt = 0; jt < 96; jt += 8) {
        float a[8];
#pragma unroll
        for (int u = 0; u < 8; ++u) a[u] = buf[lane * 100 + jt + u];
#pragma unroll
        for (int u = 0; u < 8; ++u) {
            const float* Wr = WihT + (jt + u) * 96;
#pragma unroll
            for (int i = 0; i < 8; ++i) {
                ir[i] = fmaf(a[u], Wr[kb + i], ir[i]);
                iz[i] = fmaf(a[u], Wr[32 + kb + i], iz[i]);
                in_[i] = fmaf(a[u], Wr[64 + kb + i], in_[i]);
            }
        }
    }
#pragma unroll 2
    for (int jt = 0; jt < 32; jt += 8) {
        float b[8];
#pragma unroll
        for (int u = 0; u < 8; ++u) b[u] = ht[lane][jt + u];
#pragma unroll
        for (int u = 0; u < 8; ++u) {
            const float* Wr = WhhT + (jt + u) * 96;
#pragma unroll
            for (int i = 0; i < 8; ++i) {
                hr[i] = fmaf(b[u], Wr[kb + i], hr[i]);
                hz[i] = fmaf(b[u], Wr[32 + kb + i], hz[i]);
                hn[i] = fmaf(b[u], Wr[64 + kb + i], hn[i]);
            }
        }
    }
    __syncthreads();                            // all X reads done before overwriting buf rows
#pragma unroll
    for (int i = 0; i < 8; ++i) {
        int k = kb + i;
        float r = 1.f / (1.f + __expf(-(ir[i] + bih[k] + hr[i] + bhh[k])));
        float z = 1.f / (1.f + __expf(-(iz[i] + bih[32 + k] + hz[i] + bhh[32 + k])));
        float nn = tanhf(in_[i] + bih[64 + k] + r * (hn[i] + bhh[64 + k]));
        buf[lane * 100 + k] = (1.f - z) * nn + z * ht[lane][k];
    }
    __syncthreads();
    for (int idx = tid; idx < 64 * 32; idx += 256) {
        int r = idx >> 5, c = idx & 31;
        int n = n0 + r;
        if (n < N) hout[(long)n * 32 + c] = buf[r * 100 + c];
    }
}

// ---------------- graph aggregator ----------------
__global__ void graph_agg(const float* __restrict__ h, const float* __restrict__ W1,
                          const float* __restrict__ b1, const int* __restrict__ gidx,
                          float* __restrict__ gs, int N, int chunk) {
    int k = threadIdx.x;  // 128
    int n_start = blockIdx.x * chunk;
    if (n_start >= N) return;
    int n_end = min(n_start + chunk, N);
    float acc = 0.f;
    int cur = gidx[n_start];
    for (int n = n_start; n < n_end; ++n) {
        int g = gidx[n];
        if (g != cur) { atomicAdd(&gs[cur * 128 + k], acc); acc = 0.f; cur = g; }
        float g1 = b1[k], g2 = b1[128 + k];
#pragma unroll 8
        for (int j = 0; j < 32; ++j) {
            float hv = h[(long)n * 32 + j];
            g1 = fmaf(hv, W1[j * 256 + k], g1);
            g2 = fmaf(hv, W1[j * 256 + 128 + k], g2);
        }
        acc += (1.f / (1.f + __expf(-g1))) * g2;
    }
    atomicAdd(&gs[cur * 128 + k], acc);
}

__global__ void final_gemm(const float* __restrict__ gs, const float* __restrict__ W,
                           const float* __restrict__ b, float* __restrict__ out) {
    int g = blockIdx.x, k = threadIdx.x;
    float a = b[k];
#pragma unroll 8
    for (int j = 0; j < 128; ++j) a = fmaf(gs[g * 128 + j], W[j * 128 + k], a);
    out[g * 128 + k] = a;
}

extern "C" void kernel_launch(void* const* d_in, const int* in_sizes, int n_in,
                              void* d_out, int out_size, void* d_ws, size_t ws_size,
                              hipStream_t stream) {
    const float* node_features = (const float*)d_in[0];
    const float* enc_W  = (const float*)d_in[1];
    const float* enc_b  = (const float*)d_in[2];
    const float* msg_W1 = (const float*)d_in[3];
    const float* msg_b1 = (const float*)d_in[4];
    const float* msg_W2 = (const float*)d_in[5];
    const float* msg_b2 = (const float*)d_in[6];
    const float* rmsg_W1 = (const float*)d_in[7];
    const float* rmsg_b1 = (const float*)d_in[8];
    const float* rmsg_W2 = (const float*)d_in[9];
    const float* rmsg_b2 = (const float*)d_in[10];
    const float* gru_Wih = (const float*)d_in[11];
    const float* gru_Whh = (const float*)d_in[12];
    const float* gru_bih = (const float*)d_in[13];
    const float* gru_bhh = (const float*)d_in[14];
    const float* agg_W1 = (const float*)d_in[15];
    const float* agg_b1 = (const float*)d_in[16];
    const float* agg_W2 = (const float*)d_in[17];
    const float* agg_b2 = (const float*)d_in[18];
    const int* from_idx = (const int*)d_in[19];
    const int* to_idx   = (const int*)d_in[20];
    const int* graph_idx = (const int*)d_in[21];

    const int N = in_sizes[0] / 32;
    const int E = in_sizes[19];
    const int NG = out_size / 128;
    float* out = (float*)d_out;

    char* ws = (char*)d_ws;
    auto alloc = [&](size_t b) { void* p = (void*)ws; ws += (b + 255) & ~(size_t)255; return p; };
    int* cnt_to   = (int*)alloc((size_t)N * 4);
    int* cnt_from = (int*)alloc((size_t)N * 4);
    int* off_to   = (int*)alloc((size_t)(N + 1) * 4);
    int* off_from = (int*)alloc((size_t)(N + 1) * 4);
    int* list_to  = (int*)alloc((size_t)E * 4);
    int* list_from= (int*)alloc((size_t)E * 4);
    float* h0  = (float*)alloc((size_t)N * 32 * 4);
    float* h1  = (float*)alloc((size_t)N * 32 * 4);
    unsigned* PaF = (unsigned*)alloc((size_t)N * 48 * 4);
    unsigned* PaR = (unsigned*)alloc((size_t)N * 48 * 4);
    float* PbF = (float*)alloc((size_t)N * 96 * 4);
    float* PbR = (float*)alloc((size_t)N * 96 * 4);
    float* WihT = (float*)alloc((size_t)3 * 96 * 96 * 4);
    float* WhhT = (float*)alloc((size_t)3 * 32 * 96 * 4);
    float* gs   = (float*)alloc((size_t)NG * 128 * 4);
    // rank arrays alias Pb buffers (dead before proj writes them)
    int* rank_to   = (int*)PbF;
    int* rank_from = (int*)PbR;

    hipMemsetAsync(cnt_to, 0, (size_t)N * 4, stream);
    hipMemsetAsync(cnt_from, 0, (size_t)N * 4, stream);
    hipMemsetAsync(gs, 0, (size_t)NG * 128 * 4, stream);

    int gE = (E + 255) / 256;
    count_rank_kernel<<<gE, 256, 0, stream>>>(from_idx, to_idx, cnt_to, cnt_from, rank_to, rank_from, E);
    scan2_kernel<<<2, 1024, 0, stream>>>(cnt_to, off_to, cnt_from, off_from, N);
    fill_kernel<<<gE, 256, 0, stream>>>(from_idx, to_idx, off_to, off_from, rank_to, rank_from,
                                        list_to, list_from, E);

    transpose_all<<<(3 * 96 * 96 + 3 * 32 * 96 + 255) / 256, 256, 0, stream>>>(gru_Wih, gru_Whh, WihT, WhhT);

    int gN64 = (N + 63) / 64;
    enc_gemm<<<gN64, 256, 0, stream>>>(node_features, enc_W, enc_b, h0, N);

    float* hcur = h0; float* hnext = h1;
    dim3 gProj(gN64, 2), gAgg((N + 3) / 4, 2);
    for (int l = 0; l < 3; ++l) {
        proj_kernel<<<gProj, 256, 0, stream>>>(hcur, msg_W1 + l * 6144, msg_b1 + l * 96,
                                               rmsg_W1 + l * 6144, rmsg_b1 + l * 96,
                                               PaF, PbF, PaR, PbR, N);
        agg_bf16<<<gAgg, 256, 0, stream>>>(off_to, list_to, off_from, list_from,
                                           PaF, PaR, PbF, PbR, N);
        xgru_kernel<<<gN64, 256, 0, stream>>>(PbF, PbR, msg_W2 + l * 9216, rmsg_W2 + l * 9216,
                                              msg_b2 + l * 96, rmsg_b2 + l * 96, off_to, off_from,
                                              hcur, WihT + l * 9216, WhhT + l * 3072,
                                              gru_bih + l * 96, gru_bhh + l * 96, hnext, N);
        float* t = hcur; hcur = hnext; hnext = t;
    }

    graph_agg<<<(N + 63) / 64, 128, 0, stream>>>(hcur, agg_W1, agg_b1, graph_idx, gs, N, 64);
    final_gemm<<<NG, 128, 0, stream>>>(gs, agg_W2, agg_b2, out);
}

// Round 6
// 1477.937 us; speedup vs baseline: 1.3387x; 1.1415x over previous
//
#include <hip/hip_runtime.h>

__device__ inline unsigned short f2bf(float f) {
    unsigned u = __float_as_uint(f);
    unsigned r = (u + 0x7fffu + ((u >> 16) & 1u)) >> 16;   // round-nearest-even
    return (unsigned short)r;
}

// ---------------- CSR build (rank captured in count pass; fill is atomic-free) ----------------
__global__ void count_rank_kernel(const int* __restrict__ from_idx, const int* __restrict__ to_idx,
                                  int* __restrict__ cnt_to, int* __restrict__ cnt_from,
                                  int* __restrict__ rank_to, int* __restrict__ rank_from, int E) {
    int e = blockIdx.x * blockDim.x + threadIdx.x;
    if (e >= E) return;
    int f = from_idx[e], t = to_idx[e];
    rank_to[e] = atomicAdd(&cnt_to[t], 1);
    rank_from[e] = atomicAdd(&cnt_from[f], 1);
}

__global__ void scan2_kernel(const int* __restrict__ cnt_to, int* __restrict__ off_to,
                             const int* __restrict__ cnt_from, int* __restrict__ off_from, int n) {
    const int* cnt = blockIdx.x ? cnt_from : cnt_to;
    int* off = blockIdx.x ? off_from : off_to;
    __shared__ int part[1024];
    int tid = threadIdx.x;
    int chunk = (n + 1023) >> 10;
    int beg = tid * chunk, end = min(beg + chunk, n);
    int s = 0;
    for (int i = beg; i < end; ++i) s += cnt[i];
    part[tid] = s;
    __syncthreads();
    for (int d = 1; d < 1024; d <<= 1) {
        int v = part[tid];
        int add = (tid >= d) ? part[tid - d] : 0;
        __syncthreads();
        part[tid] = v + add;
        __syncthreads();
    }
    int base = part[tid] - s;
    for (int i = beg; i < end; ++i) { off[i] = base; base += cnt[i]; }
    if (tid == 1023) off[n] = part[1023];
}

__global__ void fill_kernel(const int* __restrict__ from_idx, const int* __restrict__ to_idx,
                            const int* __restrict__ off_to, const int* __restrict__ off_from,
                            const int* __restrict__ rank_to, const int* __restrict__ rank_from,
                            int* __restrict__ list_to, int* __restrict__ list_from, int E) {
    int e = blockIdx.x * blockDim.x + threadIdx.x;
    if (e >= E) return;
    int f = from_idx[e], t = to_idx[e];
    list_to[off_to[t] + rank_to[e]] = f;
    list_from[off_from[f] + rank_from[e]] = t;
}

// ---------------- weight transposes (GRU uses x @ W.T) ----------------
__global__ void transpose_all(const float* __restrict__ Wih, const float* __restrict__ Whh,
                              float* __restrict__ WihT, float* __restrict__ WhhT) {
    int idx = blockIdx.x * 256 + threadIdx.x;
    if (idx < 3 * 96 * 96) {
        int l = idx / 9216, r = idx % 9216;
        int j = r / 96, k = r % 96;
        WihT[idx] = Wih[l * 9216 + k * 96 + j];
    } else if (idx < 3 * 96 * 96 + 3 * 32 * 96) {
        int i2 = idx - 3 * 96 * 96;
        int l = i2 / 3072, r = i2 % 3072;
        int j = r / 96, k = r % 96;
        WhhT[i2] = Whh[l * 3072 + k * 32 + j];
    }
}

// ---------------- encoder: h = IN@W + b ----------------
__global__ void __launch_bounds__(256) enc_gemm(const float* __restrict__ IN,
                                                const float* __restrict__ W, const float* __restrict__ bias,
                                                float* __restrict__ OUT, int N) {
    __shared__ float tile[64][33];
    int n0 = blockIdx.x * 64, tid = threadIdx.x;
    for (int idx = tid; idx < 64 * 32; idx += 256) {
        int r = idx >> 5, c = idx & 31;
        int n = n0 + r;
        tile[r][c] = (n < N) ? IN[(long)n * 32 + c] : 0.f;
    }
    __syncthreads();
    int lane = tid & 63, w = tid >> 6;
    float acc[8] = {0};
    const float* Wp = W + w * 8;
#pragma unroll 4
    for (int j = 0; j < 32; ++j) {
        float a = tile[lane][j];
#pragma unroll
        for (int c = 0; c < 8; ++c) acc[c] = fmaf(a, Wp[j * 32 + c], acc[c]);
    }
    int n = n0 + lane;
    if (n >= N) return;
    float* outp = OUT + (long)n * 32 + w * 8;
#pragma unroll
    for (int c = 0; c < 8; ++c) outp[c] = acc[c] + bias[w * 8 + c];
}

// ---------------- projections: Pa = h@W1[:32] (bf16 packed), Pb = h@W1[32:] + b1 (fp32); y: fwd/rev ----
__global__ void __launch_bounds__(256) proj_kernel(
    const float* __restrict__ h,
    const float* __restrict__ W1f, const float* __restrict__ b1f,
    const float* __restrict__ W1r, const float* __restrict__ b1r,
    unsigned* __restrict__ PaFu, float* __restrict__ PbF,
    unsigned* __restrict__ PaRu, float* __restrict__ PbR, int N)
{
    const float* W1 = blockIdx.y ? W1r : W1f;
    const float* b1 = blockIdx.y ? b1r : b1f;
    unsigned* PaU = blockIdx.y ? PaRu : PaFu;
    float* Pb = blockIdx.y ? PbR : PbF;
    __shared__ float tile[64][33];
    int n0 = blockIdx.x * 64, tid = threadIdx.x;
    for (int idx = tid; idx < 64 * 32; idx += 256) {
        int r = idx >> 5, c = idx & 31;
        int n = n0 + r;
        tile[r][c] = (n < N) ? h[(long)n * 32 + c] : 0.f;
    }
    __syncthreads();
    int lane = tid & 63, w = tid >> 6;
    int c0 = w * 48;                            // waves 0,1 -> Pa (src-half); 2,3 -> Pb (dst-half)
    const float* Wp = (c0 < 96) ? (W1 + c0) : (W1 + 32 * 96 + (c0 - 96));
    float acc[48];
#pragma unroll
    for (int c = 0; c < 48; ++c) acc[c] = 0.f;
#pragma unroll 4
    for (int j = 0; j < 32; ++j) {
        float a = tile[lane][j];
#pragma unroll
        for (int c = 0; c < 48; ++c) acc[c] = fmaf(a, Wp[j * 96 + c], acc[c]);
    }
    int n = n0 + lane;
    if (n >= N) return;
    if (c0 < 96) {
        unsigned* pap = PaU + (long)n * 48 + (c0 >> 1);
#pragma unroll
        for (int c = 0; c < 24; ++c)
            pap[c] = (unsigned)f2bf(acc[2 * c]) | ((unsigned)f2bf(acc[2 * c + 1]) << 16);
    } else {
        float* outp = Pb + (long)n * 96 + (c0 - 96);
#pragma unroll
        for (int c = 0; c < 48; ++c) outp[c] = acc[c] + b1[c0 - 96 + c];
    }
}

// ---------------- edge aggregation: gather packed-bf16 Pa rows (192 B), relu, accumulate ----------------
__global__ void __launch_bounds__(256) agg_bf16(
    const int* __restrict__ offF, const int* __restrict__ listF,
    const int* __restrict__ offR, const int* __restrict__ listR,
    const unsigned* __restrict__ PaF, const unsigned* __restrict__ PaR,
    float* PbF, float* PbR, int N)
{
    const int* off; const int* list; const unsigned* Pa; float* Pb;
    if (blockIdx.y == 0) { off = offF; list = listF; Pa = PaF; Pb = PbF; }
    else                 { off = offR; list = listR; Pa = PaR; Pb = PbR; }
    int n = (blockIdx.x * 256 + threadIdx.x) >> 6;
    int lane = threadIdx.x & 63;
    if (n >= N) return;
    int li = (lane < 48) ? lane : 47;           // idle lanes duplicate col 47 (same line, free)
    bool act = lane < 48;
    long pbase = (long)n * 96 + 2 * li;
    float sx = 0.f, sy = 0.f;
    if (act) { float2 s = *(const float2*)(Pb + pbase); sx = s.x; sy = s.y; }  // dst proj + b1
    float a0 = 0.f, a1 = 0.f;
    int beg = off[n], end = off[n + 1];
    int i = beg;
    for (; i + 4 <= end; i += 4) {              // 4 gathers in flight
        int s0 = __builtin_amdgcn_readfirstlane(list[i]);
        int s1 = __builtin_amdgcn_readfirstlane(list[i + 1]);
        int s2 = __builtin_amdgcn_readfirstlane(list[i + 2]);
        int s3 = __builtin_amdgcn_readfirstlane(list[i + 3]);
        unsigned u0 = Pa[(long)s0 * 48 + li];
        unsigned u1 = Pa[(long)s1 * 48 + li];
        unsigned u2 = Pa[(long)s2 * 48 + li];
        unsigned u3 = Pa[(long)s3 * 48 + li];
        a0 += fmaxf(__uint_as_float(u0 << 16) + sx, 0.f);
        a1 += fmaxf(__uint_as_float(u0 & 0xffff0000u) + sy, 0.f);
        a0 += fmaxf(__uint_as_float(u1 << 16) + sx, 0.f);
        a1 += fmaxf(__uint_as_float(u1 & 0xffff0000u) + sy, 0.f);
        a0 += fmaxf(__uint_as_float(u2 << 16) + sx, 0.f);
        a1 += fmaxf(__uint_as_float(u2 & 0xffff0000u) + sy, 0.f);
        a0 += fmaxf(__uint_as_float(u3 << 16) + sx, 0.f);
        a1 += fmaxf(__uint_as_float(u3 & 0xffff0000u) + sy, 0.f);
    }
    for (; i < end; ++i) {
        int src = __builtin_amdgcn_readfirstlane(list[i]);
        unsigned u = Pa[(long)src * 48 + li];
        a0 += fmaxf(__uint_as_float(u << 16) + sx, 0.f);
        a1 += fmaxf(__uint_as_float(u & 0xffff0000u) + sy, 0.f);
    }
    if (act) { *(float2*)(Pb + pbase) = make_float2(a0, a1); }
}

// ---------------- fused X + GRU, phased staging; stride 97 (==1 mod 32, conflict-free) ----------------
__global__ void __launch_bounds__(256, 4) xgru_kernel(
    const float* __restrict__ AF, const float* __restrict__ AR,
    const float* __restrict__ W2, const float* __restrict__ rW2,
    const float* __restrict__ b2, const float* __restrict__ rb2,
    const int* __restrict__ offF, const int* __restrict__ offR,
    const float* __restrict__ h,
    const float* __restrict__ WihT, const float* __restrict__ WhhT,
    const float* __restrict__ bih, const float* __restrict__ bhh,
    float* __restrict__ hout, int N)
{
    __shared__ float buf[64 * 97];              // AF -> AR -> X, phased (24.8 KB)
    __shared__ float ht[64][33];                // 8.4 KB; total 33.3 KB -> 4 blocks/CU
    int n0 = blockIdx.x * 64, tid = threadIdx.x;
    int lane = tid & 63, w = tid >> 6;

    for (int idx = tid; idx < 64 * 96; idx += 256) {
        int r = idx / 96, c = idx % 96;
        int n = n0 + r;
        buf[r * 97 + c] = (n < N) ? AF[(long)n * 96 + c] : 0.f;
    }
    for (int idx = tid; idx < 64 * 32; idx += 256) {
        int r = idx >> 5, c = idx & 31;
        int n = n0 + r;
        ht[r][c] = (n < N) ? h[(long)n * 32 + c] : 0.f;
    }
    __syncthreads();

    float acc[24];
#pragma unroll
    for (int c = 0; c < 24; ++c) acc[c] = 0.f;
    const float* WpF = W2 + w * 24;
#pragma unroll 4
    for (int j = 0; j < 96; ++j) {
        float a = buf[lane * 97 + j];
#pragma unroll
        for (int c = 0; c < 24; ++c) acc[c] = fmaf(a, WpF[j * 96 + c], acc[c]);
    }
    __syncthreads();                            // GEMM1 reads done; restage with AR
    for (int idx = tid; idx < 64 * 96; idx += 256) {
        int r = idx / 96, c = idx % 96;
        int n = n0 + r;
        buf[r * 97 + c] = (n < N) ? AR[(long)n * 96 + c] : 0.f;
    }
    __syncthreads();
    const float* WpR = rW2 + w * 24;
#pragma unroll 4
    for (int j = 0; j < 96; ++j) {
        float a = buf[lane * 97 + j];
#pragma unroll
        for (int c = 0; c < 24; ++c) acc[c] = fmaf(a, WpR[j * 96 + c], acc[c]);
    }
    int nb = min(n0 + lane, N - 1);
    float dF = (float)(offF[nb + 1] - offF[nb]);
    float dR = (float)(offR[nb + 1] - offR[nb]);
    __syncthreads();                            // GEMM2 reads done; buf becomes X
#pragma unroll
    for (int c = 0; c < 24; ++c)
        buf[lane * 97 + w * 24 + c] = acc[c] + dF * b2[w * 24 + c] + dR * rb2[w * 24 + c];
    __syncthreads();

    // ---- GRU ----
    int kb = w * 8;
    float ir[8], iz[8], in_[8], hr[8], hz[8], hn[8];
#pragma unroll
    for (int i = 0; i < 8; ++i) { ir[i] = iz[i] = in_[i] = hr[i] = hz[i] = hn[i] = 0.f; }
#pragma unroll 4
    for (int j = 0; j < 96; ++j) {
        float a = buf[lane * 97 + j];
        const float* Wr = WihT + j * 96;
#pragma unroll
        for (int i = 0; i < 8; ++i) {
            ir[i] = fmaf(a, Wr[kb + i], ir[i]);
            iz[i] = fmaf(a, Wr[32 + kb + i], iz[i]);
            in_[i] = fmaf(a, Wr[64 + kb + i], in_[i]);
        }
    }
#pragma unroll 4
    for (int j = 0; j < 32; ++j) {
        float b = ht[lane][j];
        const float* Wr = WhhT + j * 96;
#pragma unroll
        for (int i = 0; i < 8; ++i) {
            hr[i] = fmaf(b, Wr[kb + i], hr[i]);
            hz[i] = fmaf(b, Wr[32 + kb + i], hz[i]);
            hn[i] = fmaf(b, Wr[64 + kb + i], hn[i]);
        }
    }
    __syncthreads();                            // all X reads done before overwriting buf rows
#pragma unroll
    for (int i = 0; i < 8; ++i) {
        int k = kb + i;
        float r = 1.f / (1.f + __expf(-(ir[i] + bih[k] + hr[i] + bhh[k])));
        float z = 1.f / (1.f + __expf(-(iz[i] + bih[32 + k] + hz[i] + bhh[32 + k])));
        float nn = tanhf(in_[i] + bih[64 + k] + r * (hn[i] + bhh[64 + k]));
        buf[lane * 97 + k] = (1.f - z) * nn + z * ht[lane][k];
    }
    __syncthreads();
    for (int idx = tid; idx < 64 * 32; idx += 256) {
        int r = idx >> 5, c = idx & 31;
        int n = n0 + r;
        if (n < N) hout[(long)n * 32 + c] = buf[r * 97 + c];
    }
}

// ---------------- graph aggregator ----------------
__global__ void graph_agg(const float* __restrict__ h, const float* __restrict__ W1,
                          const float* __restrict__ b1, const int* __restrict__ gidx,
                          float* __restrict__ gs, int N, int chunk) {
    int k = threadIdx.x;  // 128
    int n_start = blockIdx.x * chunk;
    if (n_start >= N) return;
    int n_end = min(n_start + chunk, N);
    float acc = 0.f;
    int cur = gidx[n_start];
    for (int n = n_start; n < n_end; ++n) {
        int g = gidx[n];
        if (g != cur) { atomicAdd(&gs[cur * 128 + k], acc); acc = 0.f; cur = g; }
        float g1 = b1[k], g2 = b1[128 + k];
#pragma unroll 8
        for (int j = 0; j < 32; ++j) {
            float hv = h[(long)n * 32 + j];
            g1 = fmaf(hv, W1[j * 256 + k], g1);
            g2 = fmaf(hv, W1[j * 256 + 128 + k], g2);
        }
        acc += (1.f / (1.f + __expf(-g1))) * g2;
    }
    atomicAdd(&gs[cur * 128 + k], acc);
}

__global__ void final_gemm(const float* __restrict__ gs, const float* __restrict__ W,
                           const float* __restrict__ b, float* __restrict__ out) {
    int g = blockIdx.x, k = threadIdx.x;
    float a = b[k];
#pragma unroll 8
    for (int j = 0; j < 128; ++j) a = fmaf(gs[g * 128 + j], W[j * 128 + k], a);
    out[g * 128 + k] = a;
}

extern "C" void kernel_launch(void* const* d_in, const int* in_sizes, int n_in,
                              void* d_out, int out_size, void* d_ws, size_t ws_size,
                              hipStream_t stream) {
    const float* node_features = (const float*)d_in[0];
    const float* enc_W  = (const float*)d_in[1];
    const float* enc_b  = (const float*)d_in[2];
    const float* msg_W1 = (const float*)d_in[3];
    const float* msg_b1 = (const float*)d_in[4];
    const float* msg_W2 = (const float*)d_in[5];
    const float* msg_b2 = (const float*)d_in[6];
    const float* rmsg_W1 = (const float*)d_in[7];
    const float* rmsg_b1 = (const float*)d_in[8];
    const float* rmsg_W2 = (const float*)d_in[9];
    const float* rmsg_b2 = (const float*)d_in[10];
    const float* gru_Wih = (const float*)d_in[11];
    const float* gru_Whh = (const float*)d_in[12];
    const float* gru_bih = (const float*)d_in[13];
    const float* gru_bhh = (const float*)d_in[14];
    const float* agg_W1 = (const float*)d_in[15];
    const float* agg_b1 = (const float*)d_in[16];
    const float* agg_W2 = (const float*)d_in[17];
    const float* agg_b2 = (const float*)d_in[18];
    const int* from_idx = (const int*)d_in[19];
    const int* to_idx   = (const int*)d_in[20];
    const int* graph_idx = (const int*)d_in[21];

    const int N = in_sizes[0] / 32;
    const int E = in_sizes[19];
    const int NG = out_size / 128;
    float* out = (float*)d_out;

    char* ws = (char*)d_ws;
    auto alloc = [&](size_t b) { void* p = (void*)ws; ws += (b + 255) & ~(size_t)255; return p; };
    int* cnt_to   = (int*)alloc((size_t)N * 4);
    int* cnt_from = (int*)alloc((size_t)N * 4);
    int* off_to   = (int*)alloc((size_t)(N + 1) * 4);
    int* off_from = (int*)alloc((size_t)(N + 1) * 4);
    int* list_to  = (int*)alloc((size_t)E * 4);
    int* list_from= (int*)alloc((size_t)E * 4);
    float* h0  = (float*)alloc((size_t)N * 32 * 4);
    float* h1  = (float*)alloc((size_t)N * 32 * 4);
    unsigned* PaF = (unsigned*)alloc((size_t)N * 48 * 4);
    unsigned* PaR = (unsigned*)alloc((size_t)N * 48 * 4);
    float* PbF = (float*)alloc((size_t)N * 96 * 4);
    float* PbR = (float*)alloc((size_t)N * 96 * 4);
    float* WihT = (float*)alloc((size_t)3 * 96 * 96 * 4);
    float* WhhT = (float*)alloc((size_t)3 * 32 * 96 * 4);
    float* gs   = (float*)alloc((size_t)NG * 128 * 4);
    // rank arrays alias Pb buffers (dead before proj writes them)
    int* rank_to   = (int*)PbF;
    int* rank_from = (int*)PbR;

    hipMemsetAsync(cnt_to, 0, (size_t)N * 4, stream);
    hipMemsetAsync(cnt_from, 0, (size_t)N * 4, stream);
    hipMemsetAsync(gs, 0, (size_t)NG * 128 * 4, stream);

    int gE = (E + 255) / 256;
    count_rank_kernel<<<gE, 256, 0, stream>>>(from_idx, to_idx, cnt_to, cnt_from, rank_to, rank_from, E);
    scan2_kernel<<<2, 1024, 0, stream>>>(cnt_to, off_to, cnt_from, off_from, N);
    fill_kernel<<<gE, 256, 0, stream>>>(from_idx, to_idx, off_to, off_from, rank_to, rank_from,
                                        list_to, list_from, E);

    transpose_all<<<(3 * 96 * 96 + 3 * 32 * 96 + 255) / 256, 256, 0, stream>>>(gru_Wih, gru_Whh, WihT, WhhT);

    int gN64 = (N + 63) / 64;
    enc_gemm<<<gN64, 256, 0, stream>>>(node_features, enc_W, enc_b, h0, N);

    float* hcur = h0; float* hnext = h1;
    dim3 gProj(gN64, 2), gAgg((N + 3) / 4, 2);
    for (int l = 0; l < 3; ++l) {
        proj_kernel<<<gProj, 256, 0, stream>>>(hcur, msg_W1 + l * 6144, msg_b1 + l * 96,
                                               rmsg_W1 + l * 6144, rmsg_b1 + l * 96,
                                               PaF, PbF, PaR, PbR, N);
        agg_bf16<<<gAgg, 256, 0, stream>>>(off_to, list_to, off_from, list_from,
                                           PaF, PaR, PbF, PbR, N);
        xgru_kernel<<<gN64, 256, 0, stream>>>(PbF, PbR, msg_W2 + l * 9216, rmsg_W2 + l * 9216,
                                              msg_b2 + l * 96, rmsg_b2 + l * 96, off_to, off_from,
                                              hcur, WihT + l * 9216, WhhT + l * 3072,
                                              gru_bih + l * 96, gru_bhh + l * 96, hnext, N);
        float* t = hcur; hcur = hnext; hnext = t;
    }

    graph_agg<<<(N + 63) / 64, 128, 0, stream>>>(hcur, agg_W1, agg_b1, graph_idx, gs, N, 64);
    final_gemm<<<NG, 128, 0, stream>>>(gs, agg_W2, agg_b2, out);
}

// Round 7
// 812.051 us; speedup vs baseline: 2.4364x; 1.8200x over previous
//
#include <hip/hip_runtime.h>

__device__ inline unsigned short f2bf(float f) {
    unsigned u = __float_as_uint(f);
    unsigned r = (u + 0x7fffu + ((u >> 16) & 1u)) >> 16;   // round-nearest-even
    return (unsigned short)r;
}

// ---------------- CSR build (rank captured in count pass; fill is atomic-free) ----------------
__global__ void count_rank_kernel(const int* __restrict__ from_idx, const int* __restrict__ to_idx,
                                  int* __restrict__ cnt_to, int* __restrict__ cnt_from,
                                  int* __restrict__ rank_to, int* __restrict__ rank_from, int E) {
    int e = blockIdx.x * blockDim.x + threadIdx.x;
    if (e >= E) return;
    int f = from_idx[e], t = to_idx[e];
    rank_to[e] = atomicAdd(&cnt_to[t], 1);
    rank_from[e] = atomicAdd(&cnt_from[f], 1);
}

__global__ void scan2_kernel(const int* __restrict__ cnt_to, int* __restrict__ off_to,
                             const int* __restrict__ cnt_from, int* __restrict__ off_from, int n) {
    const int* cnt = blockIdx.x ? cnt_from : cnt_to;
    int* off = blockIdx.x ? off_from : off_to;
    __shared__ int part[1024];
    int tid = threadIdx.x;
    int chunk = (n + 1023) >> 10;
    int beg = tid * chunk, end = min(beg + chunk, n);
    int s = 0;
    for (int i = beg; i < end; ++i) s += cnt[i];
    part[tid] = s;
    __syncthreads();
    for (int d = 1; d < 1024; d <<= 1) {
        int v = part[tid];
        int add = (tid >= d) ? part[tid - d] : 0;
        __syncthreads();
        part[tid] = v + add;
        __syncthreads();
    }
    int base = part[tid] - s;
    for (int i = beg; i < end; ++i) { off[i] = base; base += cnt[i]; }
    if (tid == 1023) off[n] = part[1023];
}

__global__ void fill_kernel(const int* __restrict__ from_idx, const int* __restrict__ to_idx,
                            const int* __restrict__ off_to, const int* __restrict__ off_from,
                            const int* __restrict__ rank_to, const int* __restrict__ rank_from,
                            int* __restrict__ list_to, int* __restrict__ list_from, int E) {
    int e = blockIdx.x * blockDim.x + threadIdx.x;
    if (e >= E) return;
    int f = from_idx[e], t = to_idx[e];
    list_to[off_to[t] + rank_to[e]] = f;
    list_from[off_from[f] + rank_from[e]] = t;
}

// ---------------- Whh transpose: WhhT[l][j][k] = Whh[l][k][j] (j<32 input, k<96 gate) ------------
__global__ void transpose_whh(const float* __restrict__ Whh, float* __restrict__ WhhT) {
    int idx = blockIdx.x * 256 + threadIdx.x;
    if (idx >= 3 * 32 * 96) return;
    int l = idx / 3072, r = idx % 3072;
    int j = r / 96, k = r % 96;
    WhhT[idx] = Whh[l * 3072 + k * 32 + j];
}

// ---------------- compose: M1 = W2 @ Wih^T, M2 = rW2 @ Wih^T, v1 = b2 @ Wih^T, v2 = rb2 @ Wih^T --
// M1[l][j][k] = sum_m W2[l][j][m] * Wih[l][k][m]
__global__ void compose_kernel(const float* __restrict__ W2, const float* __restrict__ rW2,
                               const float* __restrict__ Wih,
                               const float* __restrict__ b2, const float* __restrict__ rb2,
                               float* __restrict__ M1, float* __restrict__ M2,
                               float* __restrict__ v12) {
    int l = blockIdx.x / 97, j = blockIdx.x % 97;
    int k = threadIdx.x;  // 96
    const float* wih = Wih + l * 9216 + k * 96;
    if (j < 96) {
        const float* w2  = W2 + l * 9216 + j * 96;   // block-uniform -> s_load
        const float* rw2 = rW2 + l * 9216 + j * 96;
        float a1 = 0.f, a2 = 0.f;
        for (int m = 0; m < 96; ++m) {
            float wv = wih[m];
            a1 = fmaf(w2[m], wv, a1);
            a2 = fmaf(rw2[m], wv, a2);
        }
        M1[l * 9216 + j * 96 + k] = a1;
        M2[l * 9216 + j * 96 + k] = a2;
    } else {
        const float* bb = b2 + l * 96;
        const float* rbb = rb2 + l * 96;
        float a1 = 0.f, a2 = 0.f;
        for (int m = 0; m < 96; ++m) {
            float wv = wih[m];
            a1 = fmaf(bb[m], wv, a1);
            a2 = fmaf(rbb[m], wv, a2);
        }
        v12[l * 192 + k] = a1;
        v12[l * 192 + 96 + k] = a2;
    }
}

// ---------------- encoder: h = IN@W + b ----------------
__global__ void __launch_bounds__(256) enc_gemm(const float* __restrict__ IN,
                                                const float* __restrict__ W, const float* __restrict__ bias,
                                                float* __restrict__ OUT, int N) {
    __shared__ float tile[64][33];
    int n0 = blockIdx.x * 64, tid = threadIdx.x;
    for (int idx = tid; idx < 64 * 32; idx += 256) {
        int r = idx >> 5, c = idx & 31;
        int n = n0 + r;
        tile[r][c] = (n < N) ? IN[(long)n * 32 + c] : 0.f;
    }
    __syncthreads();
    int lane = tid & 63;
    int w = __builtin_amdgcn_readfirstlane(tid >> 6);   // provably uniform -> scalar weight loads
    float acc[8] = {0};
    const float* Wp = W + w * 8;
#pragma unroll 4
    for (int j = 0; j < 32; ++j) {
        float a = tile[lane][j];
#pragma unroll
        for (int c = 0; c < 8; ++c) acc[c] = fmaf(a, Wp[j * 32 + c], acc[c]);
    }
    int n = n0 + lane;
    if (n >= N) return;
    float* outp = OUT + (long)n * 32 + w * 8;
#pragma unroll
    for (int c = 0; c < 8; ++c) outp[c] = acc[c] + bias[w * 8 + c];
}

// ---------------- projections: Pa = h@W1[:32] (bf16 packed), Pb = h@W1[32:] + b1 (fp32); y: fwd/rev ----
__global__ void __launch_bounds__(256) proj_kernel(
    const float* __restrict__ h,
    const float* __restrict__ W1f, const float* __restrict__ b1f,
    const float* __restrict__ W1r, const float* __restrict__ b1r,
    unsigned* __restrict__ PaFu, float* __restrict__ PbF,
    unsigned* __restrict__ PaRu, float* __restrict__ PbR, int N)
{
    const float* W1 = blockIdx.y ? W1r : W1f;
    const float* b1 = blockIdx.y ? b1r : b1f;
    unsigned* PaU = blockIdx.y ? PaRu : PaFu;
    float* Pb = blockIdx.y ? PbR : PbF;
    __shared__ float tile[64][33];
    int n0 = blockIdx.x * 64, tid = threadIdx.x;
    for (int idx = tid; idx < 64 * 32; idx += 256) {
        int r = idx >> 5, c = idx & 31;
        int n = n0 + r;
        tile[r][c] = (n < N) ? h[(long)n * 32 + c] : 0.f;
    }
    __syncthreads();
    int lane = tid & 63;
    int w = __builtin_amdgcn_readfirstlane(tid >> 6);
    int c0 = w * 48;                            // waves 0,1 -> Pa (src-half); 2,3 -> Pb (dst-half)
    const float* Wp = (c0 < 96) ? (W1 + c0) : (W1 + 32 * 96 + (c0 - 96));
    float acc[48];
#pragma unroll
    for (int c = 0; c < 48; ++c) acc[c] = 0.f;
#pragma unroll 2
    for (int j = 0; j < 32; ++j) {
        float a = tile[lane][j];
#pragma unroll
        for (int c = 0; c < 48; ++c) acc[c] = fmaf(a, Wp[j * 96 + c], acc[c]);
    }
    int n = n0 + lane;
    if (n >= N) return;
    if (c0 < 96) {
        unsigned* pap = PaU + (long)n * 48 + (c0 >> 1);
#pragma unroll
        for (int c = 0; c < 24; ++c)
            pap[c] = (unsigned)f2bf(acc[2 * c]) | ((unsigned)f2bf(acc[2 * c + 1]) << 16);
    } else {
        float* outp = Pb + (long)n * 96 + (c0 - 96);
#pragma unroll
        for (int c = 0; c < 48; ++c) outp[c] = acc[c] + b1[c0 - 96 + c];
    }
}

// ---------------- edge aggregation: gather packed-bf16 Pa rows (192 B), relu, accumulate ----------------
__global__ void __launch_bounds__(256) agg_bf16(
    const int* __restrict__ offF, const int* __restrict__ listF,
    const int* __restrict__ offR, const int* __restrict__ listR,
    const unsigned* __restrict__ PaF, const unsigned* __restrict__ PaR,
    float* PbF, float* PbR, int N)
{
    const int* off; const int* list; const unsigned* Pa; float* Pb;
    if (blockIdx.y == 0) { off = offF; list = listF; Pa = PaF; Pb = PbF; }
    else                 { off = offR; list = listR; Pa = PaR; Pb = PbR; }
    int n = __builtin_amdgcn_readfirstlane((blockIdx.x * 256 + threadIdx.x) >> 6);  // uniform node
    int lane = threadIdx.x & 63;
    if (n >= N) return;
    int li = (lane < 48) ? lane : 47;           // idle lanes duplicate col 47 (same line, free)
    bool act = lane < 48;
    long pbase = (long)n * 96 + 2 * li;
    float sx = 0.f, sy = 0.f;
    if (act) { float2 s = *(const float2*)(Pb + pbase); sx = s.x; sy = s.y; }  // dst proj + b1
    float a0 = 0.f, a1 = 0.f;
    int beg = off[n], end = off[n + 1];         // uniform -> s_load
    int i = beg;
    for (; i + 4 <= end; i += 4) {              // 4 gathers in flight
        int s0 = list[i], s1 = list[i + 1], s2 = list[i + 2], s3 = list[i + 3];  // s_loads
        unsigned u0 = Pa[(long)s0 * 48 + li];
        unsigned u1 = Pa[(long)s1 * 48 + li];
        unsigned u2 = Pa[(long)s2 * 48 + li];
        unsigned u3 = Pa[(long)s3 * 48 + li];
        a0 += fmaxf(__uint_as_float(u0 << 16) + sx, 0.f);
        a1 += fmaxf(__uint_as_float(u0 & 0xffff0000u) + sy, 0.f);
        a0 += fmaxf(__uint_as_float(u1 << 16) + sx, 0.f);
        a1 += fmaxf(__uint_as_float(u1 & 0xffff0000u) + sy, 0.f);
        a0 += fmaxf(__uint_as_float(u2 << 16) + sx, 0.f);
        a1 += fmaxf(__uint_as_float(u2 & 0xffff0000u) + sy, 0.f);
        a0 += fmaxf(__uint_as_float(u3 << 16) + sx, 0.f);
        a1 += fmaxf(__uint_as_float(u3 & 0xffff0000u) + sy, 0.f);
    }
    for (; i < end; ++i) {
        int src = list[i];
        unsigned u = Pa[(long)src * 48 + li];
        a0 += fmaxf(__uint_as_float(u << 16) + sx, 0.f);
        a1 += fmaxf(__uint_as_float(u & 0xffff0000u) + sy, 0.f);
    }
    if (act) { *(float2*)(Pb + pbase) = make_float2(a0, a1); }
}

// ---------------- fused gates+GRU: GI = AF@M1 + AR@M2 + dF*v1 + dR*v2 + bih; GH = h@Whh^T ------
// Wave w owns gate-aligned cols {g*32 + w*8 + i}; X never materialized.
__global__ void __launch_bounds__(256, 4) gru2_kernel(
    const float* __restrict__ AF, const float* __restrict__ AR,
    const float* __restrict__ M1, const float* __restrict__ M2,
    const float* __restrict__ v12,
    const int* __restrict__ offF, const int* __restrict__ offR,
    const float* __restrict__ h, const float* __restrict__ WhhT,
    const float* __restrict__ bih, const float* __restrict__ bhh,
    float* __restrict__ hout, int N)
{
    __shared__ float buf[64 * 97];              // AF -> AR staging, then h' (24.8 KB)
    __shared__ float ht[64][33];                // 8.4 KB; total 33.2 KB -> 4 blocks/CU
    int n0 = blockIdx.x * 64, tid = threadIdx.x;
    int lane = tid & 63;
    int w = __builtin_amdgcn_readfirstlane(tid >> 6);
    int w8 = w * 8;

    for (int idx = tid; idx < 64 * 96; idx += 256) {
        int r = idx / 96, c = idx % 96;
        int n = n0 + r;
        buf[r * 97 + c] = (n < N) ? AF[(long)n * 96 + c] : 0.f;
    }
    for (int idx = tid; idx < 64 * 32; idx += 256) {
        int r = idx >> 5, c = idx & 31;
        int n = n0 + r;
        ht[r][c] = (n < N) ? h[(long)n * 32 + c] : 0.f;
    }
    __syncthreads();

    float acc[24];
#pragma unroll
    for (int c = 0; c < 24; ++c) acc[c] = 0.f;
    const float* M1w = M1 + w8;
#pragma unroll 2
    for (int j = 0; j < 96; ++j) {
        float a = buf[lane * 97 + j];
        const float* Wr = M1w + j * 96;          // uniform -> s_load_dwordx8 x3
#pragma unroll
        for (int g = 0; g < 3; ++g)
#pragma unroll
            for (int i = 0; i < 8; ++i)
                acc[g * 8 + i] = fmaf(a, Wr[g * 32 + i], acc[g * 8 + i]);
    }
    __syncthreads();                            // phase1 reads done; restage AR
    for (int idx = tid; idx < 64 * 96; idx += 256) {
        int r = idx / 96, c = idx % 96;
        int n = n0 + r;
        buf[r * 97 + c] = (n < N) ? AR[(long)n * 96 + c] : 0.f;
    }
    __syncthreads();
    const float* M2w = M2 + w8;
#pragma unroll 2
    for (int j = 0; j < 96; ++j) {
        float a = buf[lane * 97 + j];
        const float* Wr = M2w + j * 96;
#pragma unroll
        for (int g = 0; g < 3; ++g)
#pragma unroll
            for (int i = 0; i < 8; ++i)
                acc[g * 8 + i] = fmaf(a, Wr[g * 32 + i], acc[g * 8 + i]);
    }
    // degree/bias corrections (v1,v2,bih uniform s_loads; dF,dR per-lane)
    int n = n0 + lane;
    int nb = (n < N) ? n : (N - 1);
    float dF = (float)(offF[nb + 1] - offF[nb]);
    float dR = (float)(offR[nb + 1] - offR[nb]);
    const float* v1 = v12;
    const float* v2 = v12 + 96;
#pragma unroll
    for (int g = 0; g < 3; ++g)
#pragma unroll
        for (int i = 0; i < 8; ++i) {
            int col = g * 32 + w8 + i;
            acc[g * 8 + i] += dF * v1[col] + dR * v2[col] + bih[col];
        }
    // GH = h @ Whh^T  (gate-aligned cols)
    float acc2[24];
#pragma unroll
    for (int c = 0; c < 24; ++c) acc2[c] = 0.f;
#pragma unroll 2
    for (int j = 0; j < 32; ++j) {
        float b = ht[lane][j];
        const float* Wr = WhhT + j * 96 + w8;
#pragma unroll
        for (int g = 0; g < 3; ++g)
#pragma unroll
            for (int i = 0; i < 8; ++i)
                acc2[g * 8 + i] = fmaf(b, Wr[g * 32 + i], acc2[g * 8 + i]);
    }
    __syncthreads();                            // all buf reads done; reuse for h'
#pragma unroll
    for (int i = 0; i < 8; ++i) {
        int c0 = w8 + i, c1 = 32 + w8 + i, c2 = 64 + w8 + i;
        float r = 1.f / (1.f + __expf(-(acc[i] + acc2[i] + bhh[c0])));
        float z = 1.f / (1.f + __expf(-(acc[8 + i] + acc2[8 + i] + bhh[c1])));
        float nn = tanhf(acc[16 + i] + r * (acc2[16 + i] + bhh[c2]));
        buf[lane * 97 + w8 + i] = (1.f - z) * nn + z * ht[lane][w8 + i];
    }
    __syncthreads();
    for (int idx = tid; idx < 64 * 32; idx += 256) {
        int r = idx >> 5, c = idx & 31;
        int n2 = n0 + r;
        if (n2 < N) hout[(long)n2 * 32 + c] = buf[r * 97 + c];
    }
}

// ---------------- graph aggregator ----------------
__global__ void graph_agg(const float* __restrict__ h, const float* __restrict__ W1,
                          const float* __restrict__ b1, const int* __restrict__ gidx,
                          float* __restrict__ gs, int N, int chunk) {
    int k = threadIdx.x;  // 128
    int n_start = blockIdx.x * chunk;
    if (n_start >= N) return;
    int n_end = min(n_start + chunk, N);
    float acc = 0.f;
    int cur = gidx[n_start];
    for (int n = n_start; n < n_end; ++n) {
        int g = gidx[n];
        if (g != cur) { atomicAdd(&gs[cur * 128 + k], acc); acc = 0.f; cur = g; }
        float g1 = b1[k], g2 = b1[128 + k];
#pragma unroll 8
        for (int j = 0; j < 32; ++j) {
            float hv = h[(long)n * 32 + j];      // block-uniform -> s_load
            g1 = fmaf(hv, W1[j * 256 + k], g1);
            g2 = fmaf(hv, W1[j * 256 + 128 + k], g2);
        }
        acc += (1.f / (1.f + __expf(-g1))) * g2;
    }
    atomicAdd(&gs[cur * 128 + k], acc);
}

__global__ void final_gemm(const float* __restrict__ gs, const float* __restrict__ W,
                           const float* __restrict__ b, float* __restrict__ out) {
    int g = blockIdx.x, k = threadIdx.x;
    float a = b[k];
#pragma unroll 8
    for (int j = 0; j < 128; ++j) a = fmaf(gs[g * 128 + j], W[j * 128 + k], a);
    out[g * 128 + k] = a;
}

extern "C" void kernel_launch(void* const* d_in, const int* in_sizes, int n_in,
                              void* d_out, int out_size, void* d_ws, size_t ws_size,
                              hipStream_t stream) {
    const float* node_features = (const float*)d_in[0];
    const float* enc_W  = (const float*)d_in[1];
    const float* enc_b  = (const float*)d_in[2];
    const float* msg_W1 = (const float*)d_in[3];
    const float* msg_b1 = (const float*)d_in[4];
    const float* msg_W2 = (const float*)d_in[5];
    const float* msg_b2 = (const float*)d_in[6];
    const float* rmsg_W1 = (const float*)d_in[7];
    const float* rmsg_b1 = (const float*)d_in[8];
    const float* rmsg_W2 = (const float*)d_in[9];
    const float* rmsg_b2 = (const float*)d_in[10];
    const float* gru_Wih = (const float*)d_in[11];
    const float* gru_Whh = (const float*)d_in[12];
    const float* gru_bih = (const float*)d_in[13];
    const float* gru_bhh = (const float*)d_in[14];
    const float* agg_W1 = (const float*)d_in[15];
    const float* agg_b1 = (const float*)d_in[16];
    const float* agg_W2 = (const float*)d_in[17];
    const float* agg_b2 = (const float*)d_in[18];
    const int* from_idx = (const int*)d_in[19];
    const int* to_idx   = (const int*)d_in[20];
    const int* graph_idx = (const int*)d_in[21];

    const int N = in_sizes[0] / 32;
    const int E = in_sizes[19];
    const int NG = out_size / 128;
    float* out = (float*)d_out;

    char* ws = (char*)d_ws;
    auto alloc = [&](size_t b) { void* p = (void*)ws; ws += (b + 255) & ~(size_t)255; return p; };
    int* cnt_to   = (int*)alloc((size_t)N * 4);
    int* cnt_from = (int*)alloc((size_t)N * 4);
    int* off_to   = (int*)alloc((size_t)(N + 1) * 4);
    int* off_from = (int*)alloc((size_t)(N + 1) * 4);
    int* list_to  = (int*)alloc((size_t)E * 4);
    int* list_from= (int*)alloc((size_t)E * 4);
    float* h0  = (float*)alloc((size_t)N * 32 * 4);
    float* h1  = (float*)alloc((size_t)N * 32 * 4);
    unsigned* PaF = (unsigned*)alloc((size_t)N * 48 * 4);
    unsigned* PaR = (unsigned*)alloc((size_t)N * 48 * 4);
    float* PbF = (float*)alloc((size_t)N * 96 * 4);
    float* PbR = (float*)alloc((size_t)N * 96 * 4);
    float* WhhT = (float*)alloc((size_t)3 * 32 * 96 * 4);
    float* M1   = (float*)alloc((size_t)3 * 96 * 96 * 4);
    float* M2   = (float*)alloc((size_t)3 * 96 * 96 * 4);
    float* v12  = (float*)alloc((size_t)3 * 192 * 4);
    float* gs   = (float*)alloc((size_t)NG * 128 * 4);
    // rank arrays alias Pb buffers (dead before proj writes them)
    int* rank_to   = (int*)PbF;
    int* rank_from = (int*)PbR;

    hipMemsetAsync(cnt_to, 0, (size_t)N * 4, stream);
    hipMemsetAsync(cnt_from, 0, (size_t)N * 4, stream);
    hipMemsetAsync(gs, 0, (size_t)NG * 128 * 4, stream);

    int gE = (E + 255) / 256;
    count_rank_kernel<<<gE, 256, 0, stream>>>(from_idx, to_idx, cnt_to, cnt_from, rank_to, rank_from, E);
    scan2_kernel<<<2, 1024, 0, stream>>>(cnt_to, off_to, cnt_from, off_from, N);
    fill_kernel<<<gE, 256, 0, stream>>>(from_idx, to_idx, off_to, off_from, rank_to, rank_from,
                                        list_to, list_from, E);

    transpose_whh<<<(3 * 32 * 96 + 255) / 256, 256, 0, stream>>>(gru_Whh, WhhT);
    compose_kernel<<<3 * 97, 96, 0, stream>>>(msg_W2, rmsg_W2, gru_Wih, msg_b2, rmsg_b2, M1, M2, v12);

    int gN64 = (N + 63) / 64;
    enc_gemm<<<gN64, 256, 0, stream>>>(node_features, enc_W, enc_b, h0, N);

    float* hcur = h0; float* hnext = h1;
    dim3 gProj(gN64, 2), gAgg((N + 3) / 4, 2);
    for (int l = 0; l < 3; ++l) {
        proj_kernel<<<gProj, 256, 0, stream>>>(hcur, msg_W1 + l * 6144, msg_b1 + l * 96,
                                               rmsg_W1 + l * 6144, rmsg_b1 + l * 96,
                                               PaF, PbF, PaR, PbR, N);
        agg_bf16<<<gAgg, 256, 0, stream>>>(off_to, list_to, off_from, list_from,
                                           PaF, PaR, PbF, PbR, N);
        gru2_kernel<<<gN64, 256, 0, stream>>>(PbF, PbR, M1 + l * 9216, M2 + l * 9216, v12 + l * 192,
                                              off_to, off_from, hcur, WhhT + l * 3072,
                                              gru_bih + l * 96, gru_bhh + l * 96, hnext, N);
        float* t = hcur; hcur = hnext; hnext = t;
    }

    graph_agg<<<(N + 63) / 64, 128, 0, stream>>>(hcur, agg_W1, agg_b1, graph_idx, gs, N, 64);
    final_gemm<<<NG, 128, 0, stream>>>(gs, agg_W2, agg_b2, out);
}

// Round 8
// 748.750 us; speedup vs baseline: 2.6424x; 1.0845x over previous
//
#include <hip/hip_runtime.h>

__device__ inline unsigned short f2bf(float f) {
    unsigned u = __float_as_uint(f);
    unsigned r = (u + 0x7fffu + ((u >> 16) & 1u)) >> 16;   // round-nearest-even
    return (unsigned short)r;
}

// ---------------- CSR build (rank captured in count pass; fill is atomic-free) ----------------
__global__ void count_rank_kernel(const int* __restrict__ from_idx, const int* __restrict__ to_idx,
                                  int* __restrict__ cnt_to, int* __restrict__ cnt_from,
                                  int* __restrict__ rank_to, int* __restrict__ rank_from, int E) {
    int e = blockIdx.x * blockDim.x + threadIdx.x;
    if (e >= E) return;
    int f = from_idx[e], t = to_idx[e];
    rank_to[e] = atomicAdd(&cnt_to[t], 1);
    rank_from[e] = atomicAdd(&cnt_from[f], 1);
}

__global__ void scan2_kernel(const int* __restrict__ cnt_to, int* __restrict__ off_to,
                             const int* __restrict__ cnt_from, int* __restrict__ off_from, int n) {
    const int* cnt = blockIdx.x ? cnt_from : cnt_to;
    int* off = blockIdx.x ? off_from : off_to;
    __shared__ int part[1024];
    int tid = threadIdx.x;
    int chunk = (n + 1023) >> 10;
    int beg = tid * chunk, end = min(beg + chunk, n);
    int s = 0;
    for (int i = beg; i < end; ++i) s += cnt[i];
    part[tid] = s;
    __syncthreads();
    for (int d = 1; d < 1024; d <<= 1) {
        int v = part[tid];
        int add = (tid >= d) ? part[tid - d] : 0;
        __syncthreads();
        part[tid] = v + add;
        __syncthreads();
    }
    int base = part[tid] - s;
    for (int i = beg; i < end; ++i) { off[i] = base; base += cnt[i]; }
    if (tid == 1023) off[n] = part[1023];
}

__global__ void fill_kernel(const int* __restrict__ from_idx, const int* __restrict__ to_idx,
                            const int* __restrict__ off_to, const int* __restrict__ off_from,
                            const int* __restrict__ rank_to, const int* __restrict__ rank_from,
                            int* __restrict__ list_to, int* __restrict__ list_from, int E) {
    int e = blockIdx.x * blockDim.x + threadIdx.x;
    if (e >= E) return;
    int f = from_idx[e], t = to_idx[e];
    list_to[off_to[t] + rank_to[e]] = f;
    list_from[off_from[f] + rank_from[e]] = t;
}

// ---------------- Whh transpose: WhhT[l][j][k] = Whh[l][k][j] (j<32 input, k<96 gate) ------------
__global__ void transpose_whh(const float* __restrict__ Whh, float* __restrict__ WhhT) {
    int idx = blockIdx.x * 256 + threadIdx.x;
    if (idx >= 3 * 32 * 96) return;
    int l = idx / 3072, r = idx % 3072;
    int j = r / 96, k = r % 96;
    WhhT[idx] = Whh[l * 3072 + k * 32 + j];
}

// ---------------- compose: M1 = W2 @ Wih^T, M2 = rW2 @ Wih^T, v1 = b2 @ Wih^T, v2 = rb2 @ Wih^T --
__global__ void compose_kernel(const float* __restrict__ W2, const float* __restrict__ rW2,
                               const float* __restrict__ Wih,
                               const float* __restrict__ b2, const float* __restrict__ rb2,
                               float* __restrict__ M1, float* __restrict__ M2,
                               float* __restrict__ v12) {
    int l = blockIdx.x / 97, j = blockIdx.x % 97;
    int k = threadIdx.x;  // 96
    const float* wih = Wih + l * 9216 + k * 96;
    if (j < 96) {
        const float* w2  = W2 + l * 9216 + j * 96;   // block-uniform -> s_load
        const float* rw2 = rW2 + l * 9216 + j * 96;
        float a1 = 0.f, a2 = 0.f;
        for (int m = 0; m < 96; ++m) {
            float wv = wih[m];
            a1 = fmaf(w2[m], wv, a1);
            a2 = fmaf(rw2[m], wv, a2);
        }
        M1[l * 9216 + j * 96 + k] = a1;
        M2[l * 9216 + j * 96 + k] = a2;
    } else {
        const float* bb = b2 + l * 96;
        const float* rbb = rb2 + l * 96;
        float a1 = 0.f, a2 = 0.f;
        for (int m = 0; m < 96; ++m) {
            float wv = wih[m];
            a1 = fmaf(bb[m], wv, a1);
            a2 = fmaf(rbb[m], wv, a2);
        }
        v12[l * 192 + k] = a1;
        v12[l * 192 + 96 + k] = a2;
    }
}

// ---------------- encoder: h = IN@W + b ----------------
__global__ void __launch_bounds__(256) enc_gemm(const float* __restrict__ IN,
                                                const float* __restrict__ W, const float* __restrict__ bias,
                                                float* __restrict__ OUT, int N) {
    __shared__ float tile[64][33];
    int n0 = blockIdx.x * 64, tid = threadIdx.x;
    for (int idx = tid; idx < 64 * 32; idx += 256) {
        int r = idx >> 5, c = idx & 31;
        int n = n0 + r;
        tile[r][c] = (n < N) ? IN[(long)n * 32 + c] : 0.f;
    }
    __syncthreads();
    int lane = tid & 63;
    int w = __builtin_amdgcn_readfirstlane(tid >> 6);   // provably uniform -> scalar weight loads
    float acc[8] = {0};
    const float* Wp = W + w * 8;
#pragma unroll 4
    for (int j = 0; j < 32; ++j) {
        float a = tile[lane][j];
#pragma unroll
        for (int c = 0; c < 8; ++c) acc[c] = fmaf(a, Wp[j * 32 + c], acc[c]);
    }
    int n = n0 + lane;
    if (n >= N) return;
    float* outp = OUT + (long)n * 32 + w * 8;
#pragma unroll
    for (int c = 0; c < 8; ++c) outp[c] = acc[c] + bias[w * 8 + c];
}

// ---------------- projections: Pa = h@W1[:32] (bf16 packed), Pb = h@W1[32:] + b1 (fp32); y: fwd/rev ----
__global__ void __launch_bounds__(256) proj_kernel(
    const float* __restrict__ h,
    const float* __restrict__ W1f, const float* __restrict__ b1f,
    const float* __restrict__ W1r, const float* __restrict__ b1r,
    unsigned* __restrict__ PaFu, float* __restrict__ PbF,
    unsigned* __restrict__ PaRu, float* __restrict__ PbR, int N)
{
    const float* W1 = blockIdx.y ? W1r : W1f;
    const float* b1 = blockIdx.y ? b1r : b1f;
    unsigned* PaU = blockIdx.y ? PaRu : PaFu;
    float* Pb = blockIdx.y ? PbR : PbF;
    __shared__ float tile[64][33];
    int n0 = blockIdx.x * 64, tid = threadIdx.x;
    for (int idx = tid; idx < 64 * 32; idx += 256) {
        int r = idx >> 5, c = idx & 31;
        int n = n0 + r;
        tile[r][c] = (n < N) ? h[(long)n * 32 + c] : 0.f;
    }
    __syncthreads();
    int lane = tid & 63;
    int w = __builtin_amdgcn_readfirstlane(tid >> 6);
    int c0 = w * 48;                            // waves 0,1 -> Pa (src-half); 2,3 -> Pb (dst-half)
    const float* Wp = (c0 < 96) ? (W1 + c0) : (W1 + 32 * 96 + (c0 - 96));
    float acc[48];
#pragma unroll
    for (int c = 0; c < 48; ++c) acc[c] = 0.f;
#pragma unroll 2
    for (int j = 0; j < 32; ++j) {
        float a = tile[lane][j];
#pragma unroll
        for (int c = 0; c < 48; ++c) acc[c] = fmaf(a, Wp[j * 96 + c], acc[c]);
    }
    int n = n0 + lane;
    if (n >= N) return;
    if (c0 < 96) {
        unsigned* pap = PaU + (long)n * 48 + (c0 >> 1);
#pragma unroll
        for (int c = 0; c < 24; ++c)
            pap[c] = (unsigned)f2bf(acc[2 * c]) | ((unsigned)f2bf(acc[2 * c + 1]) << 16);
    } else {
        float* outp = Pb + (long)n * 96 + (c0 - 96);
#pragma unroll
        for (int c = 0; c < 48; ++c) outp[c] = acc[c] + b1[c0 - 96 + c];
    }
}

// ---------------- edge aggregation: gather packed-bf16 Pa rows (192 B), relu, accumulate ----------------
__global__ void __launch_bounds__(256) agg_bf16(
    const int* __restrict__ offF, const int* __restrict__ listF,
    const int* __restrict__ offR, const int* __restrict__ listR,
    const unsigned* __restrict__ PaF, const unsigned* __restrict__ PaR,
    float* PbF, float* PbR, int N)
{
    const int* off; const int* list; const unsigned* Pa; float* Pb;
    if (blockIdx.y == 0) { off = offF; list = listF; Pa = PaF; Pb = PbF; }
    else                 { off = offR; list = listR; Pa = PaR; Pb = PbR; }
    int n = __builtin_amdgcn_readfirstlane((blockIdx.x * 256 + threadIdx.x) >> 6);  // uniform node
    int lane = threadIdx.x & 63;
    if (n >= N) return;
    int li = (lane < 48) ? lane : 47;           // idle lanes duplicate col 47 (same line, free)
    bool act = lane < 48;
    long pbase = (long)n * 96 + 2 * li;
    float sx = 0.f, sy = 0.f;
    if (act) { float2 s = *(const float2*)(Pb + pbase); sx = s.x; sy = s.y; }  // dst proj + b1
    float a0 = 0.f, a1 = 0.f;
    int beg = off[n], end = off[n + 1];         // uniform -> s_load
    int i = beg;
    for (; i + 4 <= end; i += 4) {              // 4 gathers in flight
        int s0 = list[i], s1 = list[i + 1], s2 = list[i + 2], s3 = list[i + 3];  // s_loads
        unsigned u0 = Pa[(long)s0 * 48 + li];
        unsigned u1 = Pa[(long)s1 * 48 + li];
        unsigned u2 = Pa[(long)s2 * 48 + li];
        unsigned u3 = Pa[(long)s3 * 48 + li];
        a0 += fmaxf(__uint_as_float(u0 << 16) + sx, 0.f);
        a1 += fmaxf(__uint_as_float(u0 & 0xffff0000u) + sy, 0.f);
        a0 += fmaxf(__uint_as_float(u1 << 16) + sx, 0.f);
        a1 += fmaxf(__uint_as_float(u1 & 0xffff0000u) + sy, 0.f);
        a0 += fmaxf(__uint_as_float(u2 << 16) + sx, 0.f);
        a1 += fmaxf(__uint_as_float(u2 & 0xffff0000u) + sy, 0.f);
        a0 += fmaxf(__uint_as_float(u3 << 16) + sx, 0.f);
        a1 += fmaxf(__uint_as_float(u3 & 0xffff0000u) + sy, 0.f);
    }
    for (; i < end; ++i) {
        int src = list[i];
        unsigned u = Pa[(long)src * 48 + li];
        a0 += fmaxf(__uint_as_float(u << 16) + sx, 0.f);
        a1 += fmaxf(__uint_as_float(u & 0xffff0000u) + sy, 0.f);
    }
    if (act) { *(float2*)(Pb + pbase) = make_float2(a0, a1); }
}

// ---------------- fused gates+GRU: GI = AF@M1 + AR@M2 + dF*v1 + dR*v2 + bih; GH = h@Whh^T ------
__global__ void __launch_bounds__(256, 4) gru2_kernel(
    const float* __restrict__ AF, const float* __restrict__ AR,
    const float* __restrict__ M1, const float* __restrict__ M2,
    const float* __restrict__ v12,
    const int* __restrict__ offF, const int* __restrict__ offR,
    const float* __restrict__ h, const float* __restrict__ WhhT,
    const float* __restrict__ bih, const float* __restrict__ bhh,
    float* __restrict__ hout, int N)
{
    __shared__ float buf[64 * 97];              // AF -> AR staging, then h' (24.8 KB)
    __shared__ float ht[64][33];                // 8.4 KB; total 33.2 KB -> 4 blocks/CU
    int n0 = blockIdx.x * 64, tid = threadIdx.x;
    int lane = tid & 63;
    int w = __builtin_amdgcn_readfirstlane(tid >> 6);
    int w8 = w * 8;

    for (int idx = tid; idx < 64 * 96; idx += 256) {
        int r = idx / 96, c = idx % 96;
        int n = n0 + r;
        buf[r * 97 + c] = (n < N) ? AF[(long)n * 96 + c] : 0.f;
    }
    for (int idx = tid; idx < 64 * 32; idx += 256) {
        int r = idx >> 5, c = idx & 31;
        int n = n0 + r;
        ht[r][c] = (n < N) ? h[(long)n * 32 + c] : 0.f;
    }
    __syncthreads();

    float acc[24];
#pragma unroll
    for (int c = 0; c < 24; ++c) acc[c] = 0.f;
    const float* M1w = M1 + w8;
#pragma unroll 2
    for (int j = 0; j < 96; ++j) {
        float a = buf[lane * 97 + j];
        const float* Wr = M1w + j * 96;          // uniform -> s_load
#pragma unroll
        for (int g = 0; g < 3; ++g)
#pragma unroll
            for (int i = 0; i < 8; ++i)
                acc[g * 8 + i] = fmaf(a, Wr[g * 32 + i], acc[g * 8 + i]);
    }
    __syncthreads();                            // phase1 reads done; restage AR
    for (int idx = tid; idx < 64 * 96; idx += 256) {
        int r = idx / 96, c = idx % 96;
        int n = n0 + r;
        buf[r * 97 + c] = (n < N) ? AR[(long)n * 96 + c] : 0.f;
    }
    __syncthreads();
    const float* M2w = M2 + w8;
#pragma unroll 2
    for (int j = 0; j < 96; ++j) {
        float a = buf[lane * 97 + j];
        const float* Wr = M2w + j * 96;
#pragma unroll
        for (int g = 0; g < 3; ++g)
#pragma unroll
            for (int i = 0; i < 8; ++i)
                acc[g * 8 + i] = fmaf(a, Wr[g * 32 + i], acc[g * 8 + i]);
    }
    // degree/bias corrections
    int n = n0 + lane;
    int nb = (n < N) ? n : (N - 1);
    float dF = (float)(offF[nb + 1] - offF[nb]);
    float dR = (float)(offR[nb + 1] - offR[nb]);
    const float* v1 = v12;
    const float* v2 = v12 + 96;
#pragma unroll
    for (int g = 0; g < 3; ++g)
#pragma unroll
        for (int i = 0; i < 8; ++i) {
            int col = g * 32 + w8 + i;
            acc[g * 8 + i] += dF * v1[col] + dR * v2[col] + bih[col];
        }
    // GH = h @ Whh^T  (gate-aligned cols)
    float acc2[24];
#pragma unroll
    for (int c = 0; c < 24; ++c) acc2[c] = 0.f;
#pragma unroll 2
    for (int j = 0; j < 32; ++j) {
        float b = ht[lane][j];
        const float* Wr = WhhT + j * 96 + w8;
#pragma unroll
        for (int g = 0; g < 3; ++g)
#pragma unroll
            for (int i = 0; i < 8; ++i)
                acc2[g * 8 + i] = fmaf(b, Wr[g * 32 + i], acc2[g * 8 + i]);
    }
    __syncthreads();                            // all buf reads done; reuse for h'
#pragma unroll
    for (int i = 0; i < 8; ++i) {
        int c0 = w8 + i, c1 = 32 + w8 + i, c2 = 64 + w8 + i;
        float r = 1.f / (1.f + __expf(-(acc[i] + acc2[i] + bhh[c0])));
        float z = 1.f / (1.f + __expf(-(acc[8 + i] + acc2[8 + i] + bhh[c1])));
        float nn = tanhf(acc[16 + i] + r * (acc2[16 + i] + bhh[c2]));
        buf[lane * 97 + w8 + i] = (1.f - z) * nn + z * ht[lane][w8 + i];
    }
    __syncthreads();
    for (int idx = tid; idx < 64 * 32; idx += 256) {
        int r = idx >> 5, c = idx & 31;
        int n2 = n0 + r;
        if (n2 < N) hout[(long)n2 * 32 + c] = buf[r * 97 + c];
    }
}

// ---------------- graph aggregator: weights hoisted to registers, chunk=32 ----------------
__global__ void __launch_bounds__(128) graph_agg(const float* __restrict__ h, const float* __restrict__ W1,
                          const float* __restrict__ b1, const int* __restrict__ gidx,
                          float* __restrict__ gs, int N, int chunk) {
    int k = threadIdx.x;  // 128
    int n_start = blockIdx.x * chunk;
    if (n_start >= N) return;
    int n_end = min(n_start + chunk, N);
    float w1[32], w2[32];
#pragma unroll
    for (int j = 0; j < 32; ++j) {              // hoist weights into registers (loop-invariant in n)
        w1[j] = W1[j * 256 + k];
        w2[j] = W1[j * 256 + 128 + k];
    }
    float bb1 = b1[k], bb2 = b1[128 + k];
    float acc = 0.f;
    int cur = gidx[n_start];
    for (int n = n_start; n < n_end; ++n) {
        int g = gidx[n];
        if (g != cur) { atomicAdd(&gs[cur * 128 + k], acc); acc = 0.f; cur = g; }
        float g1 = bb1, g2 = bb2;
#pragma unroll
        for (int j = 0; j < 32; ++j) {
            float hv = h[(long)n * 32 + j];      // block-uniform -> s_load
            g1 = fmaf(hv, w1[j], g1);
            g2 = fmaf(hv, w2[j], g2);
        }
        acc += (1.f / (1.f + __expf(-g1))) * g2;
    }
    atomicAdd(&gs[cur * 128 + k], acc);
}

__global__ void final_gemm(const float* __restrict__ gs, const float* __restrict__ W,
                           const float* __restrict__ b, float* __restrict__ out) {
    int g = blockIdx.x, k = threadIdx.x;
    float a = b[k];
#pragma unroll 8
    for (int j = 0; j < 128; ++j) a = fmaf(gs[g * 128 + j], W[j * 128 + k], a);
    out[g * 128 + k] = a;
}

extern "C" void kernel_launch(void* const* d_in, const int* in_sizes, int n_in,
                              void* d_out, int out_size, void* d_ws, size_t ws_size,
                              hipStream_t stream) {
    const float* node_features = (const float*)d_in[0];
    const float* enc_W  = (const float*)d_in[1];
    const float* enc_b  = (const float*)d_in[2];
    const float* msg_W1 = (const float*)d_in[3];
    const float* msg_b1 = (const float*)d_in[4];
    const float* msg_W2 = (const float*)d_in[5];
    const float* msg_b2 = (const float*)d_in[6];
    const float* rmsg_W1 = (const float*)d_in[7];
    const float* rmsg_b1 = (const float*)d_in[8];
    const float* rmsg_W2 = (const float*)d_in[9];
    const float* rmsg_b2 = (const float*)d_in[10];
    const float* gru_Wih = (const float*)d_in[11];
    const float* gru_Whh = (const float*)d_in[12];
    const float* gru_bih = (const float*)d_in[13];
    const float* gru_bhh = (const float*)d_in[14];
    const float* agg_W1 = (const float*)d_in[15];
    const float* agg_b1 = (const float*)d_in[16];
    const float* agg_W2 = (const float*)d_in[17];
    const float* agg_b2 = (const float*)d_in[18];
    const int* from_idx = (const int*)d_in[19];
    const int* to_idx   = (const int*)d_in[20];
    const int* graph_idx = (const int*)d_in[21];

    const int N = in_sizes[0] / 32;
    const int E = in_sizes[19];
    const int NG = out_size / 128;
    float* out = (float*)d_out;

    char* ws = (char*)d_ws;
    auto alloc = [&](size_t b) { void* p = (void*)ws; ws += (b + 255) & ~(size_t)255; return p; };
    int* cnt_to   = (int*)alloc((size_t)N * 4);
    int* cnt_from = (int*)alloc((size_t)N * 4);
    int* off_to   = (int*)alloc((size_t)(N + 1) * 4);
    int* off_from = (int*)alloc((size_t)(N + 1) * 4);
    int* list_to  = (int*)alloc((size_t)E * 4);
    int* list_from= (int*)alloc((size_t)E * 4);
    float* h0  = (float*)alloc((size_t)N * 32 * 4);
    float* h1  = (float*)alloc((size_t)N * 32 * 4);
    unsigned* PaF = (unsigned*)alloc((size_t)N * 48 * 4);
    unsigned* PaR = (unsigned*)alloc((size_t)N * 48 * 4);
    float* PbF = (float*)alloc((size_t)N * 96 * 4);
    float* PbR = (float*)alloc((size_t)N * 96 * 4);
    float* WhhT = (float*)alloc((size_t)3 * 32 * 96 * 4);
    float* M1   = (float*)alloc((size_t)3 * 96 * 96 * 4);
    float* M2   = (float*)alloc((size_t)3 * 96 * 96 * 4);
    float* v12  = (float*)alloc((size_t)3 * 192 * 4);
    float* gs   = (float*)alloc((size_t)NG * 128 * 4);
    // rank arrays alias Pb buffers (dead before proj writes them)
    int* rank_to   = (int*)PbF;
    int* rank_from = (int*)PbR;

    hipMemsetAsync(cnt_to, 0, (size_t)N * 4, stream);
    hipMemsetAsync(cnt_from, 0, (size_t)N * 4, stream);
    hipMemsetAsync(gs, 0, (size_t)NG * 128 * 4, stream);

    int gE = (E + 255) / 256;
    count_rank_kernel<<<gE, 256, 0, stream>>>(from_idx, to_idx, cnt_to, cnt_from, rank_to, rank_from, E);
    scan2_kernel<<<2, 1024, 0, stream>>>(cnt_to, off_to, cnt_from, off_from, N);
    fill_kernel<<<gE, 256, 0, stream>>>(from_idx, to_idx, off_to, off_from, rank_to, rank_from,
                                        list_to, list_from, E);

    transpose_whh<<<(3 * 32 * 96 + 255) / 256, 256, 0, stream>>>(gru_Whh, WhhT);
    compose_kernel<<<3 * 97, 96, 0, stream>>>(msg_W2, rmsg_W2, gru_Wih, msg_b2, rmsg_b2, M1, M2, v12);

    int gN64 = (N + 63) / 64;
    enc_gemm<<<gN64, 256, 0, stream>>>(node_features, enc_W, enc_b, h0, N);

    float* hcur = h0; float* hnext = h1;
    dim3 gProj(gN64, 2), gAgg((N + 3) / 4, 2);
    for (int l = 0; l < 3; ++l) {
        proj_kernel<<<gProj, 256, 0, stream>>>(hcur, msg_W1 + l * 6144, msg_b1 + l * 96,
                                               rmsg_W1 + l * 6144, rmsg_b1 + l * 96,
                                               PaF, PbF, PaR, PbR, N);
        agg_bf16<<<gAgg, 256, 0, stream>>>(off_to, list_to, off_from, list_from,
                                           PaF, PaR, PbF, PbR, N);
        gru2_kernel<<<gN64, 256, 0, stream>>>(PbF, PbR, M1 + l * 9216, M2 + l * 9216, v12 + l * 192,
                                              off_to, off_from, hcur, WhhT + l * 3072,
                                              gru_bih + l * 96, gru_bhh + l * 96, hnext, N);
        float* t = hcur; hcur = hnext; hnext = t;
    }

    const int chunk = 32;
    graph_agg<<<(N + chunk - 1) / chunk, 128, 0, stream>>>(hcur, agg_W1, agg_b1, graph_idx, gs, N, chunk);
    final_gemm<<<NG, 128, 0, stream>>>(gs, agg_W2, agg_b2, out);
}

// Round 9
// 734.567 us; speedup vs baseline: 2.6934x; 1.0193x over previous
//
#include <hip/hip_runtime.h>

__device__ inline unsigned short f2bf(float f) {
    unsigned u = __float_as_uint(f);
    unsigned r = (u + 0x7fffu + ((u >> 16) & 1u)) >> 16;   // round-nearest-even
    return (unsigned short)r;
}

// ---------------- CSR build (rank captured in count pass; fill is atomic-free) ----------------
__global__ void count_rank_kernel(const int* __restrict__ from_idx, const int* __restrict__ to_idx,
                                  int* __restrict__ cnt_to, int* __restrict__ cnt_from,
                                  int* __restrict__ rank_to, int* __restrict__ rank_from, int E) {
    int e = blockIdx.x * blockDim.x + threadIdx.x;
    if (e >= E) return;
    int f = from_idx[e], t = to_idx[e];
    rank_to[e] = atomicAdd(&cnt_to[t], 1);
    rank_from[e] = atomicAdd(&cnt_from[f], 1);
}

__global__ void scan2_kernel(const int* __restrict__ cnt_to, int* __restrict__ off_to,
                             const int* __restrict__ cnt_from, int* __restrict__ off_from, int n) {
    const int* cnt = blockIdx.x ? cnt_from : cnt_to;
    int* off = blockIdx.x ? off_from : off_to;
    __shared__ int part[1024];
    int tid = threadIdx.x;
    int chunk = (n + 1023) >> 10;
    int beg = tid * chunk, end = min(beg + chunk, n);
    int s = 0;
    for (int i = beg; i < end; ++i) s += cnt[i];
    part[tid] = s;
    __syncthreads();
    for (int d = 1; d < 1024; d <<= 1) {
        int v = part[tid];
        int add = (tid >= d) ? part[tid - d] : 0;
        __syncthreads();
        part[tid] = v + add;
        __syncthreads();
    }
    int base = part[tid] - s;
    for (int i = beg; i < end; ++i) { off[i] = base; base += cnt[i]; }
    if (tid == 1023) off[n] = part[1023];
}

__global__ void fill_kernel(const int* __restrict__ from_idx, const int* __restrict__ to_idx,
                            const int* __restrict__ off_to, const int* __restrict__ off_from,
                            const int* __restrict__ rank_to, const int* __restrict__ rank_from,
                            int* __restrict__ list_to, int* __restrict__ list_from, int E) {
    int e = blockIdx.x * blockDim.x + threadIdx.x;
    if (e >= E) return;
    int f = from_idx[e], t = to_idx[e];
    list_to[off_to[t] + rank_to[e]] = f;
    list_from[off_from[f] + rank_from[e]] = t;
}

// ---------------- Whh transpose: WhhT[l][j][k] = Whh[l][k][j] (j<32 input, k<96 gate) ------------
__global__ void transpose_whh(const float* __restrict__ Whh, float* __restrict__ WhhT) {
    int idx = blockIdx.x * 256 + threadIdx.x;
    if (idx >= 3 * 32 * 96) return;
    int l = idx / 3072, r = idx % 3072;
    int j = r / 96, k = r % 96;
    WhhT[idx] = Whh[l * 3072 + k * 32 + j];
}

// ---------------- compose: M1 = W2 @ Wih^T, M2 = rW2 @ Wih^T, v1 = b2 @ Wih^T, v2 = rb2 @ Wih^T --
__global__ void compose_kernel(const float* __restrict__ W2, const float* __restrict__ rW2,
                               const float* __restrict__ Wih,
                               const float* __restrict__ b2, const float* __restrict__ rb2,
                               float* __restrict__ M1, float* __restrict__ M2,
                               float* __restrict__ v12) {
    int l = blockIdx.x / 97, j = blockIdx.x % 97;
    int k = threadIdx.x;  // 96
    const float* wih = Wih + l * 9216 + k * 96;
    if (j < 96) {
        const float* w2  = W2 + l * 9216 + j * 96;   // block-uniform -> s_load
        const float* rw2 = rW2 + l * 9216 + j * 96;
        float a1 = 0.f, a2 = 0.f;
        for (int m = 0; m < 96; ++m) {
            float wv = wih[m];
            a1 = fmaf(w2[m], wv, a1);
            a2 = fmaf(rw2[m], wv, a2);
        }
        M1[l * 9216 + j * 96 + k] = a1;
        M2[l * 9216 + j * 96 + k] = a2;
    } else {
        const float* bb = b2 + l * 96;
        const float* rbb = rb2 + l * 96;
        float a1 = 0.f, a2 = 0.f;
        for (int m = 0; m < 96; ++m) {
            float wv = wih[m];
            a1 = fmaf(bb[m], wv, a1);
            a2 = fmaf(rbb[m], wv, a2);
        }
        v12[l * 192 + k] = a1;
        v12[l * 192 + 96 + k] = a2;
    }
}

// ---------------- encoder: h = IN@W + b ----------------
__global__ void __launch_bounds__(256) enc_gemm(const float* __restrict__ IN,
                                                const float* __restrict__ W, const float* __restrict__ bias,
                                                float* __restrict__ OUT, int N) {
    __shared__ float tile[64][33];
    int n0 = blockIdx.x * 64, tid = threadIdx.x;
    for (int idx = tid; idx < 64 * 32; idx += 256) {
        int r = idx >> 5, c = idx & 31;
        int n = n0 + r;
        tile[r][c] = (n < N) ? IN[(long)n * 32 + c] : 0.f;
    }
    __syncthreads();
    int lane = tid & 63;
    int w = __builtin_amdgcn_readfirstlane(tid >> 6);   // provably uniform -> scalar weight loads
    float acc[8] = {0};
    const float* Wp = W + w * 8;
#pragma unroll 4
    for (int j = 0; j < 32; ++j) {
        float a = tile[lane][j];
#pragma unroll
        for (int c = 0; c < 8; ++c) acc[c] = fmaf(a, Wp[j * 32 + c], acc[c]);
    }
    int n = n0 + lane;
    if (n >= N) return;
    float* outp = OUT + (long)n * 32 + w * 8;
#pragma unroll
    for (int c = 0; c < 8; ++c) outp[c] = acc[c] + bias[w * 8 + c];
}

// ---------------- projections: Pa = h@W1[:32] (bf16 packed), Pb = h@W1[32:] + b1 (fp32); y: fwd/rev ----
__global__ void __launch_bounds__(256) proj_kernel(
    const float* __restrict__ h,
    const float* __restrict__ W1f, const float* __restrict__ b1f,
    const float* __restrict__ W1r, const float* __restrict__ b1r,
    unsigned* __restrict__ PaFu, float* __restrict__ PbF,
    unsigned* __restrict__ PaRu, float* __restrict__ PbR, int N)
{
    const float* W1 = blockIdx.y ? W1r : W1f;
    const float* b1 = blockIdx.y ? b1r : b1f;
    unsigned* PaU = blockIdx.y ? PaRu : PaFu;
    float* Pb = blockIdx.y ? PbR : PbF;
    __shared__ float tile[64][33];
    int n0 = blockIdx.x * 64, tid = threadIdx.x;
    for (int idx = tid; idx < 64 * 32; idx += 256) {
        int r = idx >> 5, c = idx & 31;
        int n = n0 + r;
        tile[r][c] = (n < N) ? h[(long)n * 32 + c] : 0.f;
    }
    __syncthreads();
    int lane = tid & 63;
    int w = __builtin_amdgcn_readfirstlane(tid >> 6);
    int c0 = w * 48;                            // waves 0,1 -> Pa (src-half); 2,3 -> Pb (dst-half)
    const float* Wp = (c0 < 96) ? (W1 + c0) : (W1 + 32 * 96 + (c0 - 96));
    float acc[48];
#pragma unroll
    for (int c = 0; c < 48; ++c) acc[c] = 0.f;
#pragma unroll 2
    for (int j = 0; j < 32; ++j) {
        float a = tile[lane][j];
#pragma unroll
        for (int c = 0; c < 48; ++c) acc[c] = fmaf(a, Wp[j * 96 + c], acc[c]);
    }
    int n = n0 + lane;
    if (n >= N) return;
    if (c0 < 96) {
        unsigned* pap = PaU + (long)n * 48 + (c0 >> 1);
#pragma unroll
        for (int c = 0; c < 24; ++c)
            pap[c] = (unsigned)f2bf(acc[2 * c]) | ((unsigned)f2bf(acc[2 * c + 1]) << 16);
    } else {
        float* outp = Pb + (long)n * 96 + (c0 - 96);
#pragma unroll
        for (int c = 0; c < 48; ++c) outp[c] = acc[c] + b1[c0 - 96 + c];
    }
}

// ---------------- edge aggregation: gather packed-bf16 Pa rows (192 B), relu, accumulate ----------------
__global__ void __launch_bounds__(256) agg_bf16(
    const int* __restrict__ offF, const int* __restrict__ listF,
    const int* __restrict__ offR, const int* __restrict__ listR,
    const unsigned* __restrict__ PaF, const unsigned* __restrict__ PaR,
    float* PbF, float* PbR, int N)
{
    const int* off; const int* list; const unsigned* Pa; float* Pb;
    if (blockIdx.y == 0) { off = offF; list = listF; Pa = PaF; Pb = PbF; }
    else                 { off = offR; list = listR; Pa = PaR; Pb = PbR; }
    int n = __builtin_amdgcn_readfirstlane((blockIdx.x * 256 + threadIdx.x) >> 6);  // uniform node
    int lane = threadIdx.x & 63;
    if (n >= N) return;
    int li = (lane < 48) ? lane : 47;           // idle lanes duplicate col 47 (same line, free)
    bool act = lane < 48;
    long pbase = (long)n * 96 + 2 * li;
    float sx = 0.f, sy = 0.f;
    if (act) { float2 s = *(const float2*)(Pb + pbase); sx = s.x; sy = s.y; }  // dst proj + b1
    float a0 = 0.f, a1 = 0.f;
    int beg = off[n], end = off[n + 1];         // uniform -> s_load
    int i = beg;
    for (; i + 4 <= end; i += 4) {              // 4 gathers in flight
        int s0 = list[i], s1 = list[i + 1], s2 = list[i + 2], s3 = list[i + 3];  // s_loads
        unsigned u0 = Pa[(long)s0 * 48 + li];
        unsigned u1 = Pa[(long)s1 * 48 + li];
        unsigned u2 = Pa[(long)s2 * 48 + li];
        unsigned u3 = Pa[(long)s3 * 48 + li];
        a0 += fmaxf(__uint_as_float(u0 << 16) + sx, 0.f);
        a1 += fmaxf(__uint_as_float(u0 & 0xffff0000u) + sy, 0.f);
        a0 += fmaxf(__uint_as_float(u1 << 16) + sx, 0.f);
        a1 += fmaxf(__uint_as_float(u1 & 0xffff0000u) + sy, 0.f);
        a0 += fmaxf(__uint_as_float(u2 << 16) + sx, 0.f);
        a1 += fmaxf(__uint_as_float(u2 & 0xffff0000u) + sy, 0.f);
        a0 += fmaxf(__uint_as_float(u3 << 16) + sx, 0.f);
        a1 += fmaxf(__uint_as_float(u3 & 0xffff0000u) + sy, 0.f);
    }
    for (; i < end; ++i) {
        int src = list[i];
        unsigned u = Pa[(long)src * 48 + li];
        a0 += fmaxf(__uint_as_float(u << 16) + sx, 0.f);
        a1 += fmaxf(__uint_as_float(u & 0xffff0000u) + sy, 0.f);
    }
    if (act) { *(float2*)(Pb + pbase) = make_float2(a0, a1); }
}

// ---------------- fused gates+GRU, 8 waves: wave w owns 4 cols/gate ----------------
// GI = AF@M1 + AR@M2 + dF*v1 + dR*v2 + bih; GH = h@Whh^T; h' stored directly (dwordx4/lane).
__global__ void __launch_bounds__(512) gru2_kernel(
    const float* __restrict__ AF, const float* __restrict__ AR,
    const float* __restrict__ M1, const float* __restrict__ M2,
    const float* __restrict__ v12,
    const int* __restrict__ offF, const int* __restrict__ offR,
    const float* __restrict__ h, const float* __restrict__ WhhT,
    const float* __restrict__ bih, const float* __restrict__ bhh,
    float* __restrict__ hout, int N)
{
    __shared__ float buf[64 * 97];              // AF -> AR staging (24.8 KB)
    __shared__ float ht[64][33];                // 8.4 KB
    int n0 = blockIdx.x * 64, tid = threadIdx.x;
    int lane = tid & 63;
    int w = __builtin_amdgcn_readfirstlane(tid >> 6);   // 0..7
    int w4 = w * 4;

    for (int idx = tid; idx < 64 * 96; idx += 512) {
        int r = idx / 96, c = idx % 96;
        int nn = n0 + r;
        buf[r * 97 + c] = (nn < N) ? AF[(long)nn * 96 + c] : 0.f;
    }
    for (int idx = tid; idx < 64 * 32; idx += 512) {
        int r = idx >> 5, c = idx & 31;
        int nn = n0 + r;
        ht[r][c] = (nn < N) ? h[(long)nn * 32 + c] : 0.f;
    }
    __syncthreads();

    float acc[12];
#pragma unroll
    for (int c = 0; c < 12; ++c) acc[c] = 0.f;
    const float* M1w = M1 + w4;
#pragma unroll 4
    for (int j = 0; j < 96; ++j) {
        float a = buf[lane * 97 + j];
        const float* Wr = M1w + j * 96;          // uniform -> 3x s_load_dwordx4
#pragma unroll
        for (int g = 0; g < 3; ++g)
#pragma unroll
            for (int i = 0; i < 4; ++i)
                acc[g * 4 + i] = fmaf(a, Wr[g * 32 + i], acc[g * 4 + i]);
    }
    __syncthreads();                            // phase1 reads done; restage AR
    for (int idx = tid; idx < 64 * 96; idx += 512) {
        int r = idx / 96, c = idx % 96;
        int nn = n0 + r;
        buf[r * 97 + c] = (nn < N) ? AR[(long)nn * 96 + c] : 0.f;
    }
    __syncthreads();
    const float* M2w = M2 + w4;
#pragma unroll 4
    for (int j = 0; j < 96; ++j) {
        float a = buf[lane * 97 + j];
        const float* Wr = M2w + j * 96;
#pragma unroll
        for (int g = 0; g < 3; ++g)
#pragma unroll
            for (int i = 0; i < 4; ++i)
                acc[g * 4 + i] = fmaf(a, Wr[g * 32 + i], acc[g * 4 + i]);
    }
    // degree/bias corrections
    int n = n0 + lane;
    int nb = (n < N) ? n : (N - 1);
    float dF = (float)(offF[nb + 1] - offF[nb]);
    float dR = (float)(offR[nb + 1] - offR[nb]);
    const float* v1 = v12;
    const float* v2 = v12 + 96;
#pragma unroll
    for (int g = 0; g < 3; ++g)
#pragma unroll
        for (int i = 0; i < 4; ++i) {
            int col = g * 32 + w4 + i;
            acc[g * 4 + i] += dF * v1[col] + dR * v2[col] + bih[col];
        }
    // GH = h @ Whh^T  (gate-aligned cols)
    float acc2[12];
#pragma unroll
    for (int c = 0; c < 12; ++c) acc2[c] = 0.f;
#pragma unroll 4
    for (int j = 0; j < 32; ++j) {
        float b = ht[lane][j];
        const float* Wr = WhhT + j * 96 + w4;
#pragma unroll
        for (int g = 0; g < 3; ++g)
#pragma unroll
            for (int i = 0; i < 4; ++i)
                acc2[g * 4 + i] = fmaf(b, Wr[g * 32 + i], acc2[g * 4 + i]);
    }
    if (n < N) {
        float4 o;
        float ov[4];
#pragma unroll
        for (int i = 0; i < 4; ++i) {
            int c0 = w4 + i, c1 = 32 + w4 + i, c2 = 64 + w4 + i;
            float r = 1.f / (1.f + __expf(-(acc[i] + acc2[i] + bhh[c0])));
            float z = 1.f / (1.f + __expf(-(acc[4 + i] + acc2[4 + i] + bhh[c1])));
            float nn = tanhf(acc[8 + i] + r * (acc2[8 + i] + bhh[c2]));
            ov[i] = (1.f - z) * nn + z * ht[lane][w4 + i];
        }
        o.x = ov[0]; o.y = ov[1]; o.z = ov[2]; o.w = ov[3];
        *(float4*)(hout + (long)n * 32 + w4) = o;   // 16B-aligned direct store
    }
}

// ---------------- graph aggregator: weights hoisted to registers, chunk=32 ----------------
__global__ void __launch_bounds__(128) graph_agg(const float* __restrict__ h, const float* __restrict__ W1,
                          const float* __restrict__ b1, const int* __restrict__ gidx,
                          float* __restrict__ gs, int N, int chunk) {
    int k = threadIdx.x;  // 128
    int n_start = blockIdx.x * chunk;
    if (n_start >= N) return;
    int n_end = min(n_start + chunk, N);
    float w1[32], w2[32];
#pragma unroll
    for (int j = 0; j < 32; ++j) {              // hoist weights into registers (loop-invariant in n)
        w1[j] = W1[j * 256 + k];
        w2[j] = W1[j * 256 + 128 + k];
    }
    float bb1 = b1[k], bb2 = b1[128 + k];
    float acc = 0.f;
    int cur = gidx[n_start];
    for (int n = n_start; n < n_end; ++n) {
        int g = gidx[n];
        if (g != cur) { atomicAdd(&gs[cur * 128 + k], acc); acc = 0.f; cur = g; }
        float g1 = bb1, g2 = bb2;
#pragma unroll
        for (int j = 0; j < 32; ++j) {
            float hv = h[(long)n * 32 + j];      // block-uniform -> s_load
            g1 = fmaf(hv, w1[j], g1);
            g2 = fmaf(hv, w2[j], g2);
        }
        acc += (1.f / (1.f + __expf(-g1))) * g2;
    }
    atomicAdd(&gs[cur * 128 + k], acc);
}

__global__ void final_gemm(const float* __restrict__ gs, const float* __restrict__ W,
                           const float* __restrict__ b, float* __restrict__ out) {
    int g = blockIdx.x, k = threadIdx.x;
    float a = b[k];
#pragma unroll 8
    for (int j = 0; j < 128; ++j) a = fmaf(gs[g * 128 + j], W[j * 128 + k], a);
    out[g * 128 + k] = a;
}

extern "C" void kernel_launch(void* const* d_in, const int* in_sizes, int n_in,
                              void* d_out, int out_size, void* d_ws, size_t ws_size,
                              hipStream_t stream) {
    const float* node_features = (const float*)d_in[0];
    const float* enc_W  = (const float*)d_in[1];
    const float* enc_b  = (const float*)d_in[2];
    const float* msg_W1 = (const float*)d_in[3];
    const float* msg_b1 = (const float*)d_in[4];
    const float* msg_W2 = (const float*)d_in[5];
    const float* msg_b2 = (const float*)d_in[6];
    const float* rmsg_W1 = (const float*)d_in[7];
    const float* rmsg_b1 = (const float*)d_in[8];
    const float* rmsg_W2 = (const float*)d_in[9];
    const float* rmsg_b2 = (const float*)d_in[10];
    const float* gru_Wih = (const float*)d_in[11];
    const float* gru_Whh = (const float*)d_in[12];
    const float* gru_bih = (const float*)d_in[13];
    const float* gru_bhh = (const float*)d_in[14];
    const float* agg_W1 = (const float*)d_in[15];
    const float* agg_b1 = (const float*)d_in[16];
    const float* agg_W2 = (const float*)d_in[17];
    const float* agg_b2 = (const float*)d_in[18];
    const int* from_idx = (const int*)d_in[19];
    const int* to_idx   = (const int*)d_in[20];
    const int* graph_idx = (const int*)d_in[21];

    const int N = in_sizes[0] / 32;
    const int E = in_sizes[19];
    const int NG = out_size / 128;
    float* out = (float*)d_out;

    char* ws = (char*)d_ws;
    auto alloc = [&](size_t b) { void* p = (void*)ws; ws += (b + 255) & ~(size_t)255; return p; };
    int* cnt_to   = (int*)alloc((size_t)N * 4);
    int* cnt_from = (int*)alloc((size_t)N * 4);
    int* off_to   = (int*)alloc((size_t)(N + 1) * 4);
    int* off_from = (int*)alloc((size_t)(N + 1) * 4);
    int* list_to  = (int*)alloc((size_t)E * 4);
    int* list_from= (int*)alloc((size_t)E * 4);
    float* h0  = (float*)alloc((size_t)N * 32 * 4);
    float* h1  = (float*)alloc((size_t)N * 32 * 4);
    unsigned* PaF = (unsigned*)alloc((size_t)N * 48 * 4);
    unsigned* PaR = (unsigned*)alloc((size_t)N * 48 * 4);
    float* PbF = (float*)alloc((size_t)N * 96 * 4);
    float* PbR = (float*)alloc((size_t)N * 96 * 4);
    float* WhhT = (float*)alloc((size_t)3 * 32 * 96 * 4);
    float* M1   = (float*)alloc((size_t)3 * 96 * 96 * 4);
    float* M2   = (float*)alloc((size_t)3 * 96 * 96 * 4);
    float* v12  = (float*)alloc((size_t)3 * 192 * 4);
    float* gs   = (float*)alloc((size_t)NG * 128 * 4);
    // rank arrays alias Pb buffers (dead before proj writes them)
    int* rank_to   = (int*)PbF;
    int* rank_from = (int*)PbR;

    hipMemsetAsync(cnt_to, 0, (size_t)N * 4, stream);
    hipMemsetAsync(cnt_from, 0, (size_t)N * 4, stream);
    hipMemsetAsync(gs, 0, (size_t)NG * 128 * 4, stream);

    int gE = (E + 255) / 256;
    count_rank_kernel<<<gE, 256, 0, stream>>>(from_idx, to_idx, cnt_to, cnt_from, rank_to, rank_from, E);
    scan2_kernel<<<2, 1024, 0, stream>>>(cnt_to, off_to, cnt_from, off_from, N);
    fill_kernel<<<gE, 256, 0, stream>>>(from_idx, to_idx, off_to, off_from, rank_to, rank_from,
                                        list_to, list_from, E);

    transpose_whh<<<(3 * 32 * 96 + 255) / 256, 256, 0, stream>>>(gru_Whh, WhhT);
    compose_kernel<<<3 * 97, 96, 0, stream>>>(msg_W2, rmsg_W2, gru_Wih, msg_b2, rmsg_b2, M1, M2, v12);

    int gN64 = (N + 63) / 64;
    enc_gemm<<<gN64, 256, 0, stream>>>(node_features, enc_W, enc_b, h0, N);

    float* hcur = h0; float* hnext = h1;
    dim3 gProj(gN64, 2), gAgg((N + 3) / 4, 2);
    for (int l = 0; l < 3; ++l) {
        proj_kernel<<<gProj, 256, 0, stream>>>(hcur, msg_W1 + l * 6144, msg_b1 + l * 96,
                                               rmsg_W1 + l * 6144, rmsg_b1 + l * 96,
                                               PaF, PbF, PaR, PbR, N);
        agg_bf16<<<gAgg, 256, 0, stream>>>(off_to, list_to, off_from, list_from,
                                           PaF, PaR, PbF, PbR, N);
        gru2_kernel<<<gN64, 512, 0, stream>>>(PbF, PbR, M1 + l * 9216, M2 + l * 9216, v12 + l * 192,
                                              off_to, off_from, hcur, WhhT + l * 3072,
                                              gru_bih + l * 96, gru_bhh + l * 96, hnext, N);
        float* t = hcur; hcur = hnext; hnext = t;
    }

    const int chunk = 32;
    graph_agg<<<(N + chunk - 1) / chunk, 128, 0, stream>>>(hcur, agg_W1, agg_b1, graph_idx, gs, N, chunk);
    final_gemm<<<NG, 128, 0, stream>>>(gs, agg_W2, agg_b2, out);
}

// Round 10
// 669.321 us; speedup vs baseline: 2.9560x; 1.0975x over previous
//
#include <hip/hip_runtime.h>

#define SB 512  // scan tile size

__device__ inline unsigned short f2bf(float f) {
    unsigned u = __float_as_uint(f);
    unsigned r = (u + 0x7fffu + ((u >> 16) & 1u)) >> 16;   // round-nearest-even
    return (unsigned short)r;
}

// ---------------- CSR build (rank captured in count pass; fill is atomic-free) ----------------
__global__ void count_rank_kernel(const int* __restrict__ from_idx, const int* __restrict__ to_idx,
                                  int* __restrict__ cnt_to, int* __restrict__ cnt_from,
                                  int* __restrict__ rank_to, int* __restrict__ rank_from, int E) {
    int e = blockIdx.x * blockDim.x + threadIdx.x;
    if (e >= E) return;
    int f = from_idx[e], t = to_idx[e];
    rank_to[e] = atomicAdd(&cnt_to[t], 1);
    rank_from[e] = atomicAdd(&cnt_from[f], 1);
}

// ---- hierarchical scan: A) block sums, B) scan of block sums, C) block scan + base ----
__global__ void __launch_bounds__(SB) scanA_kernel(const int* __restrict__ cnt_to,
                                                   const int* __restrict__ cnt_from,
                                                   int* __restrict__ bsum, int nblk, int N) {
    const int* cnt = blockIdx.y ? cnt_from : cnt_to;
    __shared__ int s[SB];
    int tid = threadIdx.x;
    int i = blockIdx.x * SB + tid;
    s[tid] = (i < N) ? cnt[i] : 0;
    __syncthreads();
    for (int d = SB / 2; d > 0; d >>= 1) {
        if (tid < d) s[tid] += s[tid + d];
        __syncthreads();
    }
    if (tid == 0) bsum[blockIdx.y * nblk + blockIdx.x] = s[0];
}

__global__ void scanB_kernel(int* __restrict__ bsum, int* __restrict__ bbase,
                             int* __restrict__ off_to, int* __restrict__ off_from,
                             int nblk, int N) {
    // single block; serial scan of nblk values per direction (nblk ~ 98)
    int tid = threadIdx.x;
    if (tid < 2) {
        const int* bs = bsum + tid * nblk;
        int* bb = bbase + tid * nblk;
        int run = 0;
        for (int i = 0; i < nblk; ++i) { bb[i] = run; run += bs[i]; }
        if (tid == 0) off_to[N] = run; else off_from[N] = run;
    }
}

__global__ void __launch_bounds__(SB) scanC_kernel(const int* __restrict__ cnt_to,
                                                   const int* __restrict__ cnt_from,
                                                   const int* __restrict__ bbase,
                                                   int* __restrict__ off_to, int* __restrict__ off_from,
                                                   int nblk, int N) {
    const int* cnt = blockIdx.y ? cnt_from : cnt_to;
    int* off = blockIdx.y ? off_from : off_to;
    __shared__ int s[SB];
    int tid = threadIdx.x;
    int i = blockIdx.x * SB + tid;
    int v = (i < N) ? cnt[i] : 0;
    s[tid] = v;
    __syncthreads();
    for (int d = 1; d < SB; d <<= 1) {          // inclusive ladder scan
        int t = s[tid];
        int add = (tid >= d) ? s[tid - d] : 0;
        __syncthreads();
        s[tid] = t + add;
        __syncthreads();
    }
    if (i < N) off[i] = s[tid] - v + bbase[blockIdx.y * nblk + blockIdx.x];
}

__global__ void fill_kernel(const int* __restrict__ from_idx, const int* __restrict__ to_idx,
                            const int* __restrict__ off_to, const int* __restrict__ off_from,
                            const int* __restrict__ rank_to, const int* __restrict__ rank_from,
                            int* __restrict__ list_to, int* __restrict__ list_from, int E) {
    int e = blockIdx.x * blockDim.x + threadIdx.x;
    if (e >= E) return;
    int f = from_idx[e], t = to_idx[e];
    list_to[off_to[t] + rank_to[e]] = f;
    list_from[off_from[f] + rank_from[e]] = t;
}

// ---------------- Whh transpose: WhhT[l][j][k] = Whh[l][k][j] (j<32 input, k<96 gate) ------------
__global__ void transpose_whh(const float* __restrict__ Whh, float* __restrict__ WhhT) {
    int idx = blockIdx.x * 256 + threadIdx.x;
    if (idx >= 3 * 32 * 96) return;
    int l = idx / 3072, r = idx % 3072;
    int j = r / 96, k = r % 96;
    WhhT[idx] = Whh[l * 3072 + k * 32 + j];
}

// ---------------- compose: M1 = W2 @ Wih^T, M2 = rW2 @ Wih^T, v1 = b2 @ Wih^T, v2 = rb2 @ Wih^T --
__global__ void compose_kernel(const float* __restrict__ W2, const float* __restrict__ rW2,
                               const float* __restrict__ Wih,
                               const float* __restrict__ b2, const float* __restrict__ rb2,
                               float* __restrict__ M1, float* __restrict__ M2,
                               float* __restrict__ v12) {
    int l = blockIdx.x / 97, j = blockIdx.x % 97;
    int k = threadIdx.x;  // 96
    const float* wih = Wih + l * 9216 + k * 96;
    if (j < 96) {
        const float* w2  = W2 + l * 9216 + j * 96;   // block-uniform -> s_load
        const float* rw2 = rW2 + l * 9216 + j * 96;
        float a1 = 0.f, a2 = 0.f;
        for (int m = 0; m < 96; ++m) {
            float wv = wih[m];
            a1 = fmaf(w2[m], wv, a1);
            a2 = fmaf(rw2[m], wv, a2);
        }
        M1[l * 9216 + j * 96 + k] = a1;
        M2[l * 9216 + j * 96 + k] = a2;
    } else {
        const float* bb = b2 + l * 96;
        const float* rbb = rb2 + l * 96;
        float a1 = 0.f, a2 = 0.f;
        for (int m = 0; m < 96; ++m) {
            float wv = wih[m];
            a1 = fmaf(bb[m], wv, a1);
            a2 = fmaf(rbb[m], wv, a2);
        }
        v12[l * 192 + k] = a1;
        v12[l * 192 + 96 + k] = a2;
    }
}

// ---------------- encoder: h = IN@W + b ----------------
__global__ void __launch_bounds__(256) enc_gemm(const float* __restrict__ IN,
                                                const float* __restrict__ W, const float* __restrict__ bias,
                                                float* __restrict__ OUT, int N) {
    __shared__ float tile[64][33];
    int n0 = blockIdx.x * 64, tid = threadIdx.x;
    for (int idx = tid; idx < 64 * 32; idx += 256) {
        int r = idx >> 5, c = idx & 31;
        int n = n0 + r;
        tile[r][c] = (n < N) ? IN[(long)n * 32 + c] : 0.f;
    }
    __syncthreads();
    int lane = tid & 63;
    int w = __builtin_amdgcn_readfirstlane(tid >> 6);   // provably uniform -> scalar weight loads
    float acc[8] = {0};
    const float* Wp = W + w * 8;
#pragma unroll 4
    for (int j = 0; j < 32; ++j) {
        float a = tile[lane][j];
#pragma unroll
        for (int c = 0; c < 8; ++c) acc[c] = fmaf(a, Wp[j * 32 + c], acc[c]);
    }
    int n = n0 + lane;
    if (n >= N) return;
    float* outp = OUT + (long)n * 32 + w * 8;
#pragma unroll
    for (int c = 0; c < 8; ++c) outp[c] = acc[c] + bias[w * 8 + c];
}

// ---------------- projections: Pa = h@W1[:32] (bf16 packed), Pb = h@W1[32:] + b1 (fp32); y: fwd/rev ----
__global__ void __launch_bounds__(256) proj_kernel(
    const float* __restrict__ h,
    const float* __restrict__ W1f, const float* __restrict__ b1f,
    const float* __restrict__ W1r, const float* __restrict__ b1r,
    unsigned* __restrict__ PaFu, float* __restrict__ PbF,
    unsigned* __restrict__ PaRu, float* __restrict__ PbR, int N)
{
    const float* W1 = blockIdx.y ? W1r : W1f;
    const float* b1 = blockIdx.y ? b1r : b1f;
    unsigned* PaU = blockIdx.y ? PaRu : PaFu;
    float* Pb = blockIdx.y ? PbR : PbF;
    __shared__ float tile[64][33];
    int n0 = blockIdx.x * 64, tid = threadIdx.x;
    for (int idx = tid; idx < 64 * 32; idx += 256) {
        int r = idx >> 5, c = idx & 31;
        int n = n0 + r;
        tile[r][c] = (n < N) ? h[(long)n * 32 + c] : 0.f;
    }
    __syncthreads();
    int lane = tid & 63;
    int w = __builtin_amdgcn_readfirstlane(tid >> 6);
    int c0 = w * 48;                            // waves 0,1 -> Pa (src-half); 2,3 -> Pb (dst-half)
    const float* Wp = (c0 < 96) ? (W1 + c0) : (W1 + 32 * 96 + (c0 - 96));
    float acc[48];
#pragma unroll
    for (int c = 0; c < 48; ++c) acc[c] = 0.f;
#pragma unroll 2
    for (int j = 0; j < 32; ++j) {
        float a = tile[lane][j];
#pragma unroll
        for (int c = 0; c < 48; ++c) acc[c] = fmaf(a, Wp[j * 96 + c], acc[c]);
    }
    int n = n0 + lane;
    if (n >= N) return;
    if (c0 < 96) {
        unsigned* pap = PaU + (long)n * 48 + (c0 >> 1);
#pragma unroll
        for (int c = 0; c < 24; ++c)
            pap[c] = (unsigned)f2bf(acc[2 * c]) | ((unsigned)f2bf(acc[2 * c + 1]) << 16);
    } else {
        float* outp = Pb + (long)n * 96 + (c0 - 96);
#pragma unroll
        for (int c = 0; c < 48; ++c) outp[c] = acc[c] + b1[c0 - 96 + c];
    }
}

// ---------------- edge aggregation: gather packed-bf16 Pa rows (192 B), relu, accumulate ----------------
__global__ void __launch_bounds__(256) agg_bf16(
    const int* __restrict__ offF, const int* __restrict__ listF,
    const int* __restrict__ offR, const int* __restrict__ listR,
    const unsigned* __restrict__ PaF, const unsigned* __restrict__ PaR,
    float* PbF, float* PbR, int N)
{
    const int* off; const int* list; const unsigned* Pa; float* Pb;
    if (blockIdx.y == 0) { off = offF; list = listF; Pa = PaF; Pb = PbF; }
    else                 { off = offR; list = listR; Pa = PaR; Pb = PbR; }
    int n = __builtin_amdgcn_readfirstlane((blockIdx.x * 256 + threadIdx.x) >> 6);  // uniform node
    int lane = threadIdx.x & 63;
    if (n >= N) return;
    int li = (lane < 48) ? lane : 47;           // idle lanes duplicate col 47 (same line, free)
    bool act = lane < 48;
    long pbase = (long)n * 96 + 2 * li;
    float sx = 0.f, sy = 0.f;
    if (act) { float2 s = *(const float2*)(Pb + pbase); sx = s.x; sy = s.y; }  // dst proj + b1
    float a0 = 0.f, a1 = 0.f;
    int beg = off[n], end = off[n + 1];         // uniform -> s_load
    int i = beg;
    for (; i + 4 <= end; i += 4) {              // 4 gathers in flight
        int s0 = list[i], s1 = list[i + 1], s2 = list[i + 2], s3 = list[i + 3];  // s_loads
        unsigned u0 = Pa[(long)s0 * 48 + li];
        unsigned u1 = Pa[(long)s1 * 48 + li];
        unsigned u2 = Pa[(long)s2 * 48 + li];
        unsigned u3 = Pa[(long)s3 * 48 + li];
        a0 += fmaxf(__uint_as_float(u0 << 16) + sx, 0.f);
        a1 += fmaxf(__uint_as_float(u0 & 0xffff0000u) + sy, 0.f);
        a0 += fmaxf(__uint_as_float(u1 << 16) + sx, 0.f);
        a1 += fmaxf(__uint_as_float(u1 & 0xffff0000u) + sy, 0.f);
        a0 += fmaxf(__uint_as_float(u2 << 16) + sx, 0.f);
        a1 += fmaxf(__uint_as_float(u2 & 0xffff0000u) + sy, 0.f);
        a0 += fmaxf(__uint_as_float(u3 << 16) + sx, 0.f);
        a1 += fmaxf(__uint_as_float(u3 & 0xffff0000u) + sy, 0.f);
    }
    for (; i < end; ++i) {
        int src = list[i];
        unsigned u = Pa[(long)src * 48 + li];
        a0 += fmaxf(__uint_as_float(u << 16) + sx, 0.f);
        a1 += fmaxf(__uint_as_float(u & 0xffff0000u) + sy, 0.f);
    }
    if (act) { *(float2*)(Pb + pbase) = make_float2(a0, a1); }
}

// ---------------- fused gates+GRU, 8 waves: wave w owns 4 cols/gate ----------------
__global__ void __launch_bounds__(512) gru2_kernel(
    const float* __restrict__ AF, const float* __restrict__ AR,
    const float* __restrict__ M1, const float* __restrict__ M2,
    const float* __restrict__ v12,
    const int* __restrict__ offF, const int* __restrict__ offR,
    const float* __restrict__ h, const float* __restrict__ WhhT,
    const float* __restrict__ bih, const float* __restrict__ bhh,
    float* __restrict__ hout, int N)
{
    __shared__ float buf[64 * 97];              // AF -> AR staging (24.8 KB)
    __shared__ float ht[64][33];                // 8.4 KB
    int n0 = blockIdx.x * 64, tid = threadIdx.x;
    int lane = tid & 63;
    int w = __builtin_amdgcn_readfirstlane(tid >> 6);   // 0..7
    int w4 = w * 4;

    for (int idx = tid; idx < 64 * 96; idx += 512) {
        int r = idx / 96, c = idx % 96;
        int nn = n0 + r;
        buf[r * 97 + c] = (nn < N) ? AF[(long)nn * 96 + c] : 0.f;
    }
    for (int idx = tid; idx < 64 * 32; idx += 512) {
        int r = idx >> 5, c = idx & 31;
        int nn = n0 + r;
        ht[r][c] = (nn < N) ? h[(long)nn * 32 + c] : 0.f;
    }
    __syncthreads();

    float acc[12];
#pragma unroll
    for (int c = 0; c < 12; ++c) acc[c] = 0.f;
    const float* M1w = M1 + w4;
#pragma unroll 4
    for (int j = 0; j < 96; ++j) {
        float a = buf[lane * 97 + j];
        const float* Wr = M1w + j * 96;          // uniform -> 3x s_load_dwordx4
#pragma unroll
        for (int g = 0; g < 3; ++g)
#pragma unroll
            for (int i = 0; i < 4; ++i)
                acc[g * 4 + i] = fmaf(a, Wr[g * 32 + i], acc[g * 4 + i]);
    }
    __syncthreads();                            // phase1 reads done; restage AR
    for (int idx = tid; idx < 64 * 96; idx += 512) {
        int r = idx / 96, c = idx % 96;
        int nn = n0 + r;
        buf[r * 97 + c] = (nn < N) ? AR[(long)nn * 96 + c] : 0.f;
    }
    __syncthreads();
    const float* M2w = M2 + w4;
#pragma unroll 4
    for (int j = 0; j < 96; ++j) {
        float a = buf[lane * 97 + j];
        const float* Wr = M2w + j * 96;
#pragma unroll
        for (int g = 0; g < 3; ++g)
#pragma unroll
            for (int i = 0; i < 4; ++i)
                acc[g * 4 + i] = fmaf(a, Wr[g * 32 + i], acc[g * 4 + i]);
    }
    // degree/bias corrections
    int n = n0 + lane;
    int nb = (n < N) ? n : (N - 1);
    float dF = (float)(offF[nb + 1] - offF[nb]);
    float dR = (float)(offR[nb + 1] - offR[nb]);
    const float* v1 = v12;
    const float* v2 = v12 + 96;
#pragma unroll
    for (int g = 0; g < 3; ++g)
#pragma unroll
        for (int i = 0; i < 4; ++i) {
            int col = g * 32 + w4 + i;
            acc[g * 4 + i] += dF * v1[col] + dR * v2[col] + bih[col];
        }
    // GH = h @ Whh^T  (gate-aligned cols)
    float acc2[12];
#pragma unroll
    for (int c = 0; c < 12; ++c) acc2[c] = 0.f;
#pragma unroll 4
    for (int j = 0; j < 32; ++j) {
        float b = ht[lane][j];
        const float* Wr = WhhT + j * 96 + w4;
#pragma unroll
        for (int g = 0; g < 3; ++g)
#pragma unroll
            for (int i = 0; i < 4; ++i)
                acc2[g * 4 + i] = fmaf(b, Wr[g * 32 + i], acc2[g * 4 + i]);
    }
    if (n < N) {
        float4 o;
        float ov[4];
#pragma unroll
        for (int i = 0; i < 4; ++i) {
            int c0 = w4 + i, c1 = 32 + w4 + i, c2 = 64 + w4 + i;
            float r = 1.f / (1.f + __expf(-(acc[i] + acc2[i] + bhh[c0])));
            float z = 1.f / (1.f + __expf(-(acc[4 + i] + acc2[4 + i] + bhh[c1])));
            float nn = tanhf(acc[8 + i] + r * (acc2[8 + i] + bhh[c2]));
            ov[i] = (1.f - z) * nn + z * ht[lane][w4 + i];
        }
        o.x = ov[0]; o.y = ov[1]; o.z = ov[2]; o.w = ov[3];
        *(float4*)(hout + (long)n * 32 + w4) = o;   // 16B-aligned direct store
    }
}

// ---------------- graph aggregator: weights hoisted to registers, chunk=32 ----------------
__global__ void __launch_bounds__(128) graph_agg(const float* __restrict__ h, const float* __restrict__ W1,
                          const float* __restrict__ b1, const int* __restrict__ gidx,
                          float* __restrict__ gs, int N, int chunk) {
    int k = threadIdx.x;  // 128
    int n_start = blockIdx.x * chunk;
    if (n_start >= N) return;
    int n_end = min(n_start + chunk, N);
    float w1[32], w2[32];
#pragma unroll
    for (int j = 0; j < 32; ++j) {              // hoist weights into registers (loop-invariant in n)
        w1[j] = W1[j * 256 + k];
        w2[j] = W1[j * 256 + 128 + k];
    }
    float bb1 = b1[k], bb2 = b1[128 + k];
    float acc = 0.f;
    int cur = gidx[n_start];
    for (int n = n_start; n < n_end; ++n) {
        int g = gidx[n];
        if (g != cur) { atomicAdd(&gs[cur * 128 + k], acc); acc = 0.f; cur = g; }
        float g1 = bb1, g2 = bb2;
#pragma unroll
        for (int j = 0; j < 32; ++j) {
            float hv = h[(long)n * 32 + j];      // block-uniform -> s_load
            g1 = fmaf(hv, w1[j], g1);
            g2 = fmaf(hv, w2[j], g2);
        }
        acc += (1.f / (1.f + __expf(-g1))) * g2;
    }
    atomicAdd(&gs[cur * 128 + k], acc);
}

__global__ void final_gemm(const float* __restrict__ gs, const float* __restrict__ W,
                           const float* __restrict__ b, float* __restrict__ out) {
    int g = blockIdx.x, k = threadIdx.x;
    float a = b[k];
#pragma unroll 8
    for (int j = 0; j < 128; ++j) a = fmaf(gs[g * 128 + j], W[j * 128 + k], a);
    out[g * 128 + k] = a;
}

extern "C" void kernel_launch(void* const* d_in, const int* in_sizes, int n_in,
                              void* d_out, int out_size, void* d_ws, size_t ws_size,
                              hipStream_t stream) {
    const float* node_features = (const float*)d_in[0];
    const float* enc_W  = (const float*)d_in[1];
    const float* enc_b  = (const float*)d_in[2];
    const float* msg_W1 = (const float*)d_in[3];
    const float* msg_b1 = (const float*)d_in[4];
    const float* msg_W2 = (const float*)d_in[5];
    const float* msg_b2 = (const float*)d_in[6];
    const float* rmsg_W1 = (const float*)d_in[7];
    const float* rmsg_b1 = (const float*)d_in[8];
    const float* rmsg_W2 = (const float*)d_in[9];
    const float* rmsg_b2 = (const float*)d_in[10];
    const float* gru_Wih = (const float*)d_in[11];
    const float* gru_Whh = (const float*)d_in[12];
    const float* gru_bih = (const float*)d_in[13];
    const float* gru_bhh = (const float*)d_in[14];
    const float* agg_W1 = (const float*)d_in[15];
    const float* agg_b1 = (const float*)d_in[16];
    const float* agg_W2 = (const float*)d_in[17];
    const float* agg_b2 = (const float*)d_in[18];
    const int* from_idx = (const int*)d_in[19];
    const int* to_idx   = (const int*)d_in[20];
    const int* graph_idx = (const int*)d_in[21];

    const int N = in_sizes[0] / 32;
    const int E = in_sizes[19];
    const int NG = out_size / 128;
    float* out = (float*)d_out;

    char* ws = (char*)d_ws;
    auto alloc = [&](size_t b) { void* p = (void*)ws; ws += (b + 255) & ~(size_t)255; return p; };
    int* cnt_to   = (int*)alloc((size_t)N * 4);
    int* cnt_from = (int*)alloc((size_t)N * 4);
    int* off_to   = (int*)alloc((size_t)(N + 1) * 4);
    int* off_from = (int*)alloc((size_t)(N + 1) * 4);
    int* list_to  = (int*)alloc((size_t)E * 4);
    int* list_from= (int*)alloc((size_t)E * 4);
    float* h0  = (float*)alloc((size_t)N * 32 * 4);
    float* h1  = (float*)alloc((size_t)N * 32 * 4);
    unsigned* PaF = (unsigned*)alloc((size_t)N * 48 * 4);
    unsigned* PaR = (unsigned*)alloc((size_t)N * 48 * 4);
    float* PbF = (float*)alloc((size_t)N * 96 * 4);
    float* PbR = (float*)alloc((size_t)N * 96 * 4);
    float* WhhT = (float*)alloc((size_t)3 * 32 * 96 * 4);
    float* M1   = (float*)alloc((size_t)3 * 96 * 96 * 4);
    float* M2   = (float*)alloc((size_t)3 * 96 * 96 * 4);
    float* v12  = (float*)alloc((size_t)3 * 192 * 4);
    float* gs   = (float*)alloc((size_t)NG * 128 * 4);
    const int nblk = (N + SB - 1) / SB;
    int* bsum  = (int*)alloc((size_t)2 * nblk * 4);
    int* bbase = (int*)alloc((size_t)2 * nblk * 4);
    // rank arrays alias Pb buffers (dead before proj writes them)
    int* rank_to   = (int*)PbF;
    int* rank_from = (int*)PbR;

    hipMemsetAsync(cnt_to, 0, (size_t)N * 4, stream);
    hipMemsetAsync(cnt_from, 0, (size_t)N * 4, stream);
    hipMemsetAsync(gs, 0, (size_t)NG * 128 * 4, stream);

    int gE = (E + 255) / 256;
    count_rank_kernel<<<gE, 256, 0, stream>>>(from_idx, to_idx, cnt_to, cnt_from, rank_to, rank_from, E);
    dim3 gScan(nblk, 2);
    scanA_kernel<<<gScan, SB, 0, stream>>>(cnt_to, cnt_from, bsum, nblk, N);
    scanB_kernel<<<1, 64, 0, stream>>>(bsum, bbase, off_to, off_from, nblk, N);
    scanC_kernel<<<gScan, SB, 0, stream>>>(cnt_to, cnt_from, bbase, off_to, off_from, nblk, N);
    fill_kernel<<<gE, 256, 0, stream>>>(from_idx, to_idx, off_to, off_from, rank_to, rank_from,
                                        list_to, list_from, E);

    transpose_whh<<<(3 * 32 * 96 + 255) / 256, 256, 0, stream>>>(gru_Whh, WhhT);
    compose_kernel<<<3 * 97, 96, 0, stream>>>(msg_W2, rmsg_W2, gru_Wih, msg_b2, rmsg_b2, M1, M2, v12);

    int gN64 = (N + 63) / 64;
    enc_gemm<<<gN64, 256, 0, stream>>>(node_features, enc_W, enc_b, h0, N);

    float* hcur = h0; float* hnext = h1;
    dim3 gProj(gN64, 2), gAgg((N + 3) / 4, 2);
    for (int l = 0; l < 3; ++l) {
        proj_kernel<<<gProj, 256, 0, stream>>>(hcur, msg_W1 + l * 6144, msg_b1 + l * 96,
                                               rmsg_W1 + l * 6144, rmsg_b1 + l * 96,
                                               PaF, PbF, PaR, PbR, N);
        agg_bf16<<<gAgg, 256, 0, stream>>>(off_to, list_to, off_from, list_from,
                                           PaF, PaR, PbF, PbR, N);
        gru2_kernel<<<gN64, 512, 0, stream>>>(PbF, PbR, M1 + l * 9216, M2 + l * 9216, v12 + l * 192,
                                              off_to, off_from, hcur, WhhT + l * 3072,
                                              gru_bih + l * 96, gru_bhh + l * 96, hnext, N);
        float* t = hcur; hcur = hnext; hnext = t;
    }

    const int chunk = 32;
    graph_agg<<<(N + chunk - 1) / chunk, 128, 0, stream>>>(hcur, agg_W1, agg_b1, graph_idx, gs, N, chunk);
    final_gemm<<<NG, 128, 0, stream>>>(gs, agg_W2, agg_b2, out);
}